// Round 15
// baseline (453.824 us; speedup 1.0000x reference)
//
#include <hip/hip_runtime.h>
#include <math.h>

#define NCLS 64
#define KS 5
#define DD 256
#define NQ 8192   // NCLS*128
#define KNB 10
#define QK 12     // per-chunk candidate list depth (need >=10 for exact containment)
#define NCH 8     // column chunks per row (1024 cols each)
#define CAND 96   // NCH * QK

typedef __attribute__((ext_vector_type(8))) short short8;   // 8 bf16 bit-patterns (4 VGPRs)
typedef __attribute__((ext_vector_type(4))) float f32x4;    // MFMA C/D frag

// row index in x (fp32 row units) of query g
__device__ __forceinline__ int qrow(int g) { return (g >> 7) * 133 + KS + (g & 127); }

__device__ __forceinline__ unsigned short bf16_rne(float f) {
    unsigned int u = __float_as_uint(f);
    u += 0x7fffu + ((u >> 16) & 1u);
    return (unsigned short)(u >> 16);
}

__device__ __forceinline__ float blk_reduce_sum(float v, float* red) {
    int t = threadIdx.x;
    red[t] = v; __syncthreads();
    for (int off = 128; off > 0; off >>= 1) {
        if (t < off) red[t] += red[t + off];
        __syncthreads();
    }
    float r = red[0];
    __syncthreads();
    return r;
}

__device__ __forceinline__ float blk_reduce_max(float v, float* red) {
    int t = threadIdx.x;
    red[t] = v; __syncthreads();
    for (int off = 128; off > 0; off >>= 1) {
        if (t < off) red[t] = fmaxf(red[t], red[t + off]);
        __syncthreads();
    }
    float r = red[0];
    __syncthreads();
    return r;
}

// ---------- K1: proto, pn, self_sim ----------
__global__ __launch_bounds__(256) void proto_kernel(const float* __restrict__ x,
                                                    float* proto, float* pn, float* selfs) {
    __shared__ float red[256];
    int c = blockIdx.x, t = threadIdx.x;
    float s = 0.f;
    for (int j = 0; j < KS; j++) s += x[(long)(c * 133 + j) * DD + t];
    float p = s / 5.0f;
    proto[c * DD + t] = p;
    float n2 = blk_reduce_sum(p * p, red);
    float pv = p / sqrtf(n2);
    pn[c * DD + t] = pv;
    float ss = blk_reduce_sum(pv * pv, red);
    if (t == 0) selfs[c] = ss;
}

// ---------- K2: FUSED split + pre_sim argmax — low-barrier version ----------
__global__ __launch_bounds__(256) void presim_kernel(const float* __restrict__ x,
                                                     const float* __restrict__ pn,
                                                     unsigned short* __restrict__ xh,
                                                     float* __restrict__ qInv,
                                                     float* pre_max, int* pre_label) {
    __shared__ __align__(16) float qs2[272];
    __shared__ float red4[4];
    __shared__ float part[256];
    __shared__ float sims[64];
    int g = blockIdx.x, t = threadIdx.x;
    const int lane = t & 63, wv = t >> 6;
    float v = x[(long)qrow(g) * DD + t];
    qs2[t + (t >> 6) * 4] = v;
    float v2 = v * v;
    #pragma unroll
    for (int off = 32; off > 0; off >>= 1) v2 += __shfl_xor(v2, off);
    if (lane == 0) red4[wv] = v2;
    __syncthreads();                               // publishes qs2 + red4
    float n2 = red4[0] + red4[1] + red4[2] + red4[3];
    float inv = 1.f / sqrtf(n2);
    xh[g * DD + t] = bf16_rne(v * inv);
    if (t == 0) qInv[g] = inv;
    int c = t >> 2, tl = t & 3;
    float s = 0.f;
    const float* qb = qs2 + tl * 68;
    const float4* pp = (const float4*)(pn + c * DD + tl * 64);
    #pragma unroll
    for (int u4 = 0; u4 < 16; u4++) {
        float4 a = *(const float4*)(qb + u4 * 4);
        float4 b = pp[u4];
        s += a.x * b.x; s += a.y * b.y; s += a.z * b.z; s += a.w * b.w;
    }
    part[t] = s; __syncthreads();
    if (tl == 0) sims[c] = part[t] + part[t + 1] + part[t + 2] + part[t + 3];
    __syncthreads();
    if (t < 64) {
        float bv = sims[t]; int bi = t;
        #pragma unroll
        for (int off = 32; off > 0; off >>= 1) {
            float ov = __shfl_xor(bv, off);
            int   oi = __shfl_xor(bi, off);
            bool take = (ov > bv) || (ov == bv && oi < bi);
            bv = take ? ov : bv;
            bi = take ? oi : bi;
        }
        if (t == 0) { pre_max[g] = bv * inv; pre_label[g] = bi; }
    }
}

// ---------- K3: adapted prototypes — LDS-compacted member list ----------
__global__ __launch_bounds__(256) void adapt_proto_kernel(const float* __restrict__ x,
                                                          const float* __restrict__ proto,
                                                          const float* __restrict__ selfs,
                                                          const float* __restrict__ pre_max,
                                                          const int* __restrict__ pre_label,
                                                          float* apn) {
    __shared__ int lst[NQ];
    __shared__ float red[256];
    __shared__ int cnt_s;
    int c = blockIdx.x, t = threadIdx.x;
    if (t == 0) cnt_s = 0;
    __syncthreads();
    float lm = -INFINITY;
    for (int g = t; g < NQ; g += 256) {
        if (pre_label[g] == c) {
            int p = atomicAdd(&cnt_s, 1);
            lst[p] = g;
            lm = fmaxf(lm, pre_max[g]);
        }
    }
    float m = fmaxf(blk_reduce_max(lm, red), selfs[c]);   // barrier publishes lst/cnt_s
    int cnt = cnt_s;
    float ls = 0.f;
    for (int e = t; e < cnt; e += 256) ls += expf(pre_max[lst[e]] - m);
    float es = expf(selfs[c] - m);
    float Z = blk_reduce_sum(ls, red) + es;
    float a0 = es * proto[c * DD + t], a1 = 0.f, a2 = 0.f, a3 = 0.f;
    int e = 0;
    for (; e + 3 < cnt; e += 4) {
        int g0 = lst[e], g1 = lst[e + 1], g2 = lst[e + 2], g3 = lst[e + 3];
        float w0 = expf(pre_max[g0] - m), w1 = expf(pre_max[g1] - m);
        float w2 = expf(pre_max[g2] - m), w3 = expf(pre_max[g3] - m);
        a0 += w0 * x[(long)qrow(g0) * DD + t];
        a1 += w1 * x[(long)qrow(g1) * DD + t];
        a2 += w2 * x[(long)qrow(g2) * DD + t];
        a3 += w3 * x[(long)qrow(g3) * DD + t];
    }
    for (; e < cnt; e++) {
        int g0 = lst[e];
        a0 += expf(pre_max[g0] - m) * x[(long)qrow(g0) * DD + t];
    }
    float ap = ((a0 + a1) + (a2 + a3)) / Z;
    float n2 = blk_reduce_sum(ap * ap, red);
    apn[c * DD + t] = ap / sqrtf(n2);
}

// ---------- K4: bf16 MFMA coarse cosines — BATCH-BITONIC top-12 scan ----------
// (R12 verified: simtopk off the top-5. Unchanged this round.)
#define CASD(A, B) { unsigned int _x = (A), _y = (B); (A) = _x > _y ? _x : _y; (B) = _x > _y ? _y : _x; }
#define CASA(A, B) { unsigned int _x = (A), _y = (B); (A) = _x < _y ? _x : _y; (B) = _x < _y ? _y : _x; }

#define COMPUTE_TILE_L(LBUF, TILE)                                                 \
    {                                                                              \
        f32x4 accE = {2.f, 2.f, 2.f, 2.f};                                         \
        f32x4 accO = {0.f, 0.f, 0.f, 0.f};                                         \
        _Pragma("unroll")                                                          \
        for (int kc = 0; kc < 8; kc += 2) {                                        \
            short8 cfe = *(const short8*)((LBUF) + ((nn << 8) + ((((kc + 0) * 4 + qd) ^ xm) << 3))); \
            short8 cfo = *(const short8*)((LBUF) + ((nn << 8) + ((((kc + 1) * 4 + qd) ^ xm) << 3))); \
            accE = __builtin_amdgcn_mfma_f32_16x16x32_bf16(cfe, qh[kc + 0], accE, 0, 0, 0); \
            accO = __builtin_amdgcn_mfma_f32_16x16x32_bf16(cfo, qh[kc + 1], accO, 0, 0, 0); \
        }                                                                          \
        const unsigned int cb_ = (unsigned int)((TILE) * 16 + 4 * qd);             \
        unsigned int v0 = (__float_as_uint(accE[0] + accO[0]) & 0xFFFFFC00u) | (cb_ + 0); \
        unsigned int v1 = (__float_as_uint(accE[1] + accO[1]) & 0xFFFFFC00u) | (cb_ + 1); \
        unsigned int v2 = (__float_as_uint(accE[2] + accO[2]) & 0xFFFFFC00u) | (cb_ + 2); \
        unsigned int v3 = (__float_as_uint(accE[3] + accO[3]) & 0xFFFFFC00u) | (cb_ + 3); \
        /* sort batch ascending: v0<=v1<=v2<=v3 */                                 \
        CASA(v0, v1) CASA(v2, v3) CASA(v0, v2) CASA(v1, v3) CASA(v1, v2)           \
        /* split16 (valley keys[0..11]++v[0..3]); (i,i+8) for i<4 are no-ops */    \
        unsigned int t4 = keys[4], t5 = keys[5], t6 = keys[6], t7 = keys[7];       \
        unsigned int b4 = t4 < v0 ? t4 : v0; t4 = t4 > v0 ? t4 : v0;               \
        unsigned int b5 = t5 < v1 ? t5 : v1; t5 = t5 > v1 ? t5 : v1;               \
        unsigned int b6 = t6 < v2 ? t6 : v2; t6 = t6 > v2 ? t6 : v2;               \
        unsigned int b7 = t7 < v3 ? t7 : v3; t7 = t7 > v3 ? t7 : v3;               \
        /* sort top-8 [keys0..3, t4..7] desc (bitonic) */                          \
        CASD(keys[0], t4) CASD(keys[1], t5) CASD(keys[2], t6) CASD(keys[3], t7)    \
        CASD(keys[0], keys[2]) CASD(keys[1], keys[3]) CASD(t4, t6) CASD(t5, t7)    \
        CASD(keys[0], keys[1]) CASD(keys[2], keys[3]) CASD(t4, t5) CASD(t6, t7)    \
        keys[4] = t4; keys[5] = t5; keys[6] = t6; keys[7] = t7;                    \
        /* bottom-8 [keys8..11, b4..7] bitonic: top-4 via split (max only) */      \
        unsigned int B0 = keys[8]  > b4 ? keys[8]  : b4;                           \
        unsigned int B1 = keys[9]  > b5 ? keys[9]  : b5;                           \
        unsigned int B2 = keys[10] > b6 ? keys[10] : b6;                           \
        unsigned int B3 = keys[11] > b7 ? keys[11] : b7;                           \
        CASD(B0, B2) CASD(B1, B3) CASD(B0, B1) CASD(B2, B3)                        \
        keys[8] = B0; keys[9] = B1; keys[10] = B2; keys[11] = B3;                  \
    }

#define GLOAD(RA, RB, TL)                                                          \
    {                                                                              \
        const unsigned short* tb = xh + ((size_t)(col0 + (TL) * 16) << 8);         \
        RA = *(const uint4*)(tb + (G0 << 3));                                      \
        RB = *(const uint4*)(tb + (G1 << 3));                                      \
    }

#define DSWRITE(P, RA, RB)                                                         \
    {                                                                              \
        *(uint4*)((P) + (u0 << 3)) = RA;                                           \
        *(uint4*)((P) + (u1 << 3)) = RB;                                           \
    }

__global__ __launch_bounds__(256, 4) void simtopk_kernel(const unsigned short* __restrict__ xh,
                                                         int* __restrict__ topi4) {
    __shared__ uint4 smem4[2048];   // 32 KB: 2 buffers x 2 tiles; dump alias 13.3KB
    unsigned short* Tb = (unsigned short*)smem4;

    const int t = threadIdx.x;
    const int b = blockIdx.x;
    const int rb = b >> 3;          // 128 row-blocks of 64 rows
    const int ch = b & 7;           // column chunk (== XCD id under round-robin: L2-local)
    const int row0 = rb * 64;
    const int col0 = ch * 1024;

    const int wv = t >> 6;
    const int lane = t & 63;
    const int qd = lane >> 4;
    const int nn = lane & 15;
    const int xm = nn & 7;

    // staging geometry: tile = 512 x 16B units; thread handles G0=t, G1=256+t
    const int G0 = t, G1 = 256 + t;
    const int r0r = G0 >> 5, c0u = G0 & 31;
    const int u0 = r0r * 32 + (c0u ^ (r0r & 7));
    const int r1r = G1 >> 5, c1u = G1 & 31;
    const int u1 = r1r * 32 + (c1u ^ (r1r & 7));

    // Query fragments (MFMA B operand): lane holds Q[n=nn][k=kc*32+qd*8 ..+7]
    const int arow = (row0 + wv * 16 + nn) * DD;
    short8 qh[8];
    #pragma unroll
    for (int kc = 0; kc < 8; kc++)
        qh[kc] = *(const short8*)(xh + arow + kc * 32 + qd * 8);

    unsigned int keys[QK];
    #pragma unroll
    for (int s = 0; s < QK; s++) keys[s] = 0u;

    uint4 RA, RB, RC, RD;
    GLOAD(RA, RB, 0)
    GLOAD(RC, RD, 1)
    DSWRITE(Tb, RA, RB)
    DSWRITE(Tb + 4096, RC, RD)
    __syncthreads();                         // tiles 0,1 ready in buffer 0

    #pragma unroll 1
    for (int p = 0; p < 32; ++p) {
        const int cur = (p & 1) << 13;       // 0 / 8192 shorts (16KB buffers)
        if (p < 31) { GLOAD(RA, RB, 2 * p + 2) GLOAD(RC, RD, 2 * p + 3) }
        COMPUTE_TILE_L(Tb + cur, 2 * p)
        COMPUTE_TILE_L(Tb + cur + 4096, 2 * p + 1)
        if (p < 31) {
            DSWRITE(Tb + (cur ^ 8192), RA, RB)
            DSWRITE(Tb + (cur ^ 8192) + 4096, RC, RD)
        }
        __syncthreads();                     // publishes pair p+1; orders reads of pair p
    }

    // dump (wave-private region, in-order DS: no barrier) + 4-list merge.
    unsigned int* dw = (unsigned int*)smem4 + wv * 832;
    #pragma unroll
    for (int s = 0; s < QK; s++) dw[lane * 13 + s] = keys[s];
    if (lane < 16) {
        const int g = row0 + wv * 16 + lane;
        const int b0 = (lane +  0) * 13;
        const int b1 = (lane + 16) * 13;
        const int b2 = (lane + 32) * 13;
        const int b3 = (lane + 48) * 13;
        int p0 = 0, p1 = 0, p2 = 0, p3 = 0;
        for (int s = 0; s < QK; s++) {
            unsigned int v0 = (p0 < QK) ? dw[b0 + p0] : 0u;
            unsigned int v1 = (p1 < QK) ? dw[b1 + p1] : 0u;
            unsigned int v2 = (p2 < QK) ? dw[b2 + p2] : 0u;
            unsigned int v3 = (p3 < QK) ? dw[b3 + p3] : 0u;
            unsigned int bv = v0; int bw = 0;
            if (v1 > bv) { bv = v1; bw = 1; }
            if (v2 > bv) { bv = v2; bw = 2; }
            if (v3 > bv) { bv = v3; bw = 3; }
            topi4[g * CAND + ch * QK + s] = col0 + (int)(bv & 1023u);
            if (bw == 0) p0++; else if (bw == 1) p1++; else if (bw == 2) p2++; else p3++;
        }
    }
}

// ---------- K5: rescoring — PER-THREAD full-row dots (no shuffle reduce) ----------
// R14 counters: VALUBusy 31%, MfmaUtil 0, occ 72% -> the hidden saturated pipe
// is DS: 18K wave-level shfl ops/CU (~110K cyc at 5.8cyc ds-swizzle) from the
// 6-step butterfly per candidate. Fix: thread t computes candidate t's FULL
// 256-dot as a private stream (4 independent accumulators, unroll 8, 16 loads
// in flight) -> ZERO cross-lane ops in scoring. Line traffic is unchanged
// (1536 lines/query either way); R4's scatter failure was ILP=1, not pattern.
// Block = 256 thr = 2 queries (96 active each); butterfly top-10 kept (2K DS).
__global__ __launch_bounds__(256, 4) void rescore_kernel(const float* __restrict__ x,
                                                         const float* __restrict__ qInv,
                                                         const int* __restrict__ topi4,
                                                         float* __restrict__ topv,
                                                         int* __restrict__ topi) {
    __shared__ float sc[2][CAND];
    __shared__ int   si[2][CAND];
    const int t = threadIdx.x;
    const int tg  = t >> 7;              // query sub-block 0..1
    const int tid = t & 127;             // 0..127 (96 active)
    const int g = blockIdx.x * 2 + tg;
    if (tid < CAND) {
        int j = topi4[g * CAND + tid];
        j = ((unsigned)j < NQ) ? j : 0;
        const float4* a4 = (const float4*)(x + (long)qrow(g) * DD);   // wave-uniform
        const float4* b4 = (const float4*)(x + (long)qrow(j) * DD);   // per-lane stream
        float ax = 0.f, ay = 0.f, az = 0.f, aw = 0.f;
        #pragma unroll 8
        for (int k = 0; k < DD / 4; k++) {
            float4 a = a4[k], b = b4[k];
            ax = fmaf(a.x, b.x, ax);
            ay = fmaf(a.y, b.y, ay);
            az = fmaf(a.z, b.z, az);
            aw = fmaf(a.w, b.w, aw);
        }
        sc[tg][tid] = (((ax + ay) + (az + aw)) * qInv[j]) * qInv[g];
        si[tg][tid] = j;
    }
    __syncthreads();
    // top-10: waves 0 and 2 handle queries 0 and 1 (64-lane butterfly argmax)
    const int wv = t >> 6;
    const int lane = t & 63;
    if ((wv & 1) == 0) {
        const int q = wv >> 1;
        const int gg = blockIdx.x * 2 + q;
        float v0 = sc[q][lane];
        int   i0 = si[q][lane];
        float v1 = -INFINITY; int i1 = 0x7fffffff;
        if (lane < CAND - 64) { v1 = sc[q][64 + lane]; i1 = si[q][64 + lane]; }
        #pragma unroll 1
        for (int s = 0; s < KNB; ++s) {
            bool sel1 = (v1 > v0) || (v1 == v0 && i1 < i0);
            float bv = sel1 ? v1 : v0;
            int   bi = sel1 ? i1 : i0;
            #pragma unroll
            for (int off = 32; off > 0; off >>= 1) {
                float ov = __shfl_xor(bv, off);
                int   oi = __shfl_xor(bi, off);
                bool take = (ov > bv) || (ov == bv && oi < bi);
                bv = take ? ov : bv;
                bi = take ? oi : bi;
            }
            if (lane == 0) { topv[gg * KNB + s] = bv; topi[gg * KNB + s] = bi; }
            if (i0 == bi) v0 = -INFINITY;
            if (i1 == bi) v1 = -INFINITY;
        }
    }
}

// ---------- K6: mutual-kNN softmax, adapted query, final cos sims ----------
// (R14 verified: off the top-5. Unchanged this round.)
__global__ __launch_bounds__(256, 8) void final_kernel(const float* __restrict__ x,
                                                       const float* __restrict__ apn,
                                                       const float* __restrict__ topv,
                                                       const int* __restrict__ topi,
                                                       const float* __restrict__ tao_raw,
                                                       float* out) {
    __shared__ float tv[KNB]; __shared__ int ti[KNB]; __shared__ float w[KNB];
    __shared__ int mutf[KNB * KNB];
    __shared__ __align__(16) float aq2[272];
    __shared__ float red4[4];
    __shared__ float part[256];
    int i = blockIdx.x, t = threadIdx.x;
    const int lane = t & 63, wv = t >> 6;
    if (t < KNB) {
        tv[t] = topv[i * KNB + t];
        int j = topi[i * KNB + t];
        ti[t] = ((unsigned)j < NQ) ? j : 0;
    }
    __syncthreads();
    if (t < KNB * KNB) {                        // parallel mutual: 100 loads in flight
        const int s = t / KNB, u = t - s * KNB;
        mutf[t] = (topi[ti[s] * KNB + u] == i) ? 1 : 0;
    }
    __syncthreads();
    if (t < 16) {                               // OR-reduce flags + wave softmax
        float val = -INFINITY;
        if (t < KNB) {
            const int* mf = &mutf[t * KNB];
            int any = mf[0] | mf[1] | mf[2] | mf[3] | mf[4]
                    | mf[5] | mf[6] | mf[7] | mf[8] | mf[9];
            val = any ? tv[t] : -INFINITY;
        }
        float m = val;
        #pragma unroll
        for (int off = 8; off > 0; off >>= 1) m = fmaxf(m, __shfl_xor(m, off));
        float e = (t < KNB) ? expf(val - m) : 0.f;
        float Z = e;
        #pragma unroll
        for (int off = 8; off > 0; off >>= 1) Z += __shfl_xor(Z, off);
        if (t < KNB) w[t] = e / Z;
    }
    __syncthreads();
    // preload weights + indices to registers, then batch all 10 row gathers
    float wr[KNB]; int tr[KNB];
    #pragma unroll
    for (int s = 0; s < KNB; s++) { wr[s] = w[s]; tr[s] = ti[s]; }
    float xv[KNB];
    #pragma unroll
    for (int s = 0; s < KNB; s++) xv[s] = x[(long)qrow(tr[s]) * DD + t];
    float a = 0.f;
    #pragma unroll
    for (int s = 0; s < KNB; s++) a += wr[s] * xv[s];
    aq2[t + (t >> 6) * 4] = a;
    float v2 = a * a;
    #pragma unroll
    for (int off = 32; off > 0; off >>= 1) v2 += __shfl_xor(v2, off);
    if (lane == 0) red4[wv] = v2;
    __syncthreads();                            // publishes aq2 + red4
    float n2 = red4[0] + red4[1] + red4[2] + red4[3];
    float inv = 1.f / sqrtf(n2);
    int c = t >> 2, tl = t & 3;
    float sdot = 0.f;
    const float* aqb = aq2 + tl * 68;
    const float4* ap4 = (const float4*)(apn + c * DD + tl * 64);
    #pragma unroll
    for (int u4 = 0; u4 < 16; u4++) {
        float4 av = *(const float4*)(aqb + u4 * 4);
        float4 pv = ap4[u4];
        sdot += av.x * pv.x; sdot += av.y * pv.y; sdot += av.z * pv.z; sdot += av.w * pv.w;
    }
    part[t] = sdot; __syncthreads();
    if (tl == 0) {
        float sv = part[t] + part[t + 1] + part[t + 2] + part[t + 3];
        out[i * NCLS + c] = tao_raw[0] * sv * inv;
    }
}

extern "C" void kernel_launch(void* const* d_in, const int* in_sizes, int n_in,
                              void* d_out, int out_size, void* d_ws, size_t ws_size,
                              hipStream_t stream) {
    (void)in_sizes; (void)n_in; (void)out_size;
    const float* x   = (const float*)d_in[0];
    const float* tao = (const float*)d_in[1];
    float* out = (float*)d_out;

    char* ws = (char*)d_ws;
    size_t off = 0;
    auto carve = [&](size_t bytes) {
        void* p = ws + off;
        off = (off + bytes + 255) & ~(size_t)255;
        return p;
    };
    float*          proto   = (float*)carve(NCLS * DD * 4);
    float*          pn      = (float*)carve(NCLS * DD * 4);
    float*          selfs   = (float*)carve(NCLS * 4);
    float*          qInv    = (float*)carve(NQ * 4);
    float*          pre_max = (float*)carve(NQ * 4);
    int*            pre_lab = (int*)carve(NQ * 4);
    float*          apn     = (float*)carve(NCLS * DD * 4);
    unsigned short* xh      = (unsigned short*)carve((size_t)NQ * DD * 2);
    int*            topi4   = (int*)carve((size_t)NQ * CAND * 4);
    float*          topv    = (float*)carve((size_t)NQ * KNB * 4);
    int*            topi    = (int*)carve((size_t)NQ * KNB * 4);
    if (off > ws_size) return;

    proto_kernel<<<NCLS, 256, 0, stream>>>(x, proto, pn, selfs);
    presim_kernel<<<NQ, 256, 0, stream>>>(x, pn, xh, qInv, pre_max, pre_lab);
    adapt_proto_kernel<<<NCLS, 256, 0, stream>>>(x, proto, selfs, pre_max, pre_lab, apn);
    simtopk_kernel<<<NQ / 64 * NCH, 256, 0, stream>>>(xh, topi4);
    rescore_kernel<<<NQ / 2, 256, 0, stream>>>(x, qInv, topi4, topv, topi);
    final_kernel<<<NQ, 256, 0, stream>>>(x, apn, topv, topi, tao, out);
}

// Round 16
// 354.682 us; speedup vs baseline: 1.2795x; 1.2795x over previous
//
#include <hip/hip_runtime.h>
#include <math.h>

#define NCLS 64
#define KS 5
#define DD 256
#define NQ 8192   // NCLS*128
#define KNB 10
#define QK 12     // per-chunk candidate list depth (need >=10 for exact containment)
#define NCH 8     // column chunks per row (1024 cols each)
#define CAND 96   // NCH * QK

typedef __attribute__((ext_vector_type(8))) short short8;   // 8 bf16 bit-patterns (4 VGPRs)
typedef __attribute__((ext_vector_type(4))) float f32x4;    // MFMA C/D frag

// row index in x (fp32 row units) of query g
__device__ __forceinline__ int qrow(int g) { return (g >> 7) * 133 + KS + (g & 127); }

__device__ __forceinline__ unsigned short bf16_rne(float f) {
    unsigned int u = __float_as_uint(f);
    u += 0x7fffu + ((u >> 16) & 1u);
    return (unsigned short)(u >> 16);
}

__device__ __forceinline__ float blk_reduce_sum(float v, float* red) {
    int t = threadIdx.x;
    red[t] = v; __syncthreads();
    for (int off = 128; off > 0; off >>= 1) {
        if (t < off) red[t] += red[t + off];
        __syncthreads();
    }
    float r = red[0];
    __syncthreads();
    return r;
}

__device__ __forceinline__ float blk_reduce_max(float v, float* red) {
    int t = threadIdx.x;
    red[t] = v; __syncthreads();
    for (int off = 128; off > 0; off >>= 1) {
        if (t < off) red[t] = fmaxf(red[t], red[t + off]);
        __syncthreads();
    }
    float r = red[0];
    __syncthreads();
    return r;
}

// ---------- K1: proto, pn, self_sim ----------
__global__ __launch_bounds__(256) void proto_kernel(const float* __restrict__ x,
                                                    float* proto, float* pn, float* selfs) {
    __shared__ float red[256];
    int c = blockIdx.x, t = threadIdx.x;
    float s = 0.f;
    for (int j = 0; j < KS; j++) s += x[(long)(c * 133 + j) * DD + t];
    float p = s / 5.0f;
    proto[c * DD + t] = p;
    float n2 = blk_reduce_sum(p * p, red);
    float pv = p / sqrtf(n2);
    pn[c * DD + t] = pv;
    float ss = blk_reduce_sum(pv * pv, red);
    if (t == 0) selfs[c] = ss;
}

// ---------- K2: FUSED split + pre_sim argmax — low-barrier version ----------
__global__ __launch_bounds__(256) void presim_kernel(const float* __restrict__ x,
                                                     const float* __restrict__ pn,
                                                     unsigned short* __restrict__ xh,
                                                     float* __restrict__ qInv,
                                                     float* pre_max, int* pre_label) {
    __shared__ __align__(16) float qs2[272];
    __shared__ float red4[4];
    __shared__ float part[256];
    __shared__ float sims[64];
    int g = blockIdx.x, t = threadIdx.x;
    const int lane = t & 63, wv = t >> 6;
    float v = x[(long)qrow(g) * DD + t];
    qs2[t + (t >> 6) * 4] = v;
    float v2 = v * v;
    #pragma unroll
    for (int off = 32; off > 0; off >>= 1) v2 += __shfl_xor(v2, off);
    if (lane == 0) red4[wv] = v2;
    __syncthreads();                               // publishes qs2 + red4
    float n2 = red4[0] + red4[1] + red4[2] + red4[3];
    float inv = 1.f / sqrtf(n2);
    xh[g * DD + t] = bf16_rne(v * inv);
    if (t == 0) qInv[g] = inv;
    int c = t >> 2, tl = t & 3;
    float s = 0.f;
    const float* qb = qs2 + tl * 68;
    const float4* pp = (const float4*)(pn + c * DD + tl * 64);
    #pragma unroll
    for (int u4 = 0; u4 < 16; u4++) {
        float4 a = *(const float4*)(qb + u4 * 4);
        float4 b = pp[u4];
        s += a.x * b.x; s += a.y * b.y; s += a.z * b.z; s += a.w * b.w;
    }
    part[t] = s; __syncthreads();
    if (tl == 0) sims[c] = part[t] + part[t + 1] + part[t + 2] + part[t + 3];
    __syncthreads();
    if (t < 64) {
        float bv = sims[t]; int bi = t;
        #pragma unroll
        for (int off = 32; off > 0; off >>= 1) {
            float ov = __shfl_xor(bv, off);
            int   oi = __shfl_xor(bi, off);
            bool take = (ov > bv) || (ov == bv && oi < bi);
            bv = take ? ov : bv;
            bi = take ? oi : bi;
        }
        if (t == 0) { pre_max[g] = bv * inv; pre_label[g] = bi; }
    }
}

// ---------- K3: adapted prototypes — LDS-compacted member list ----------
__global__ __launch_bounds__(256) void adapt_proto_kernel(const float* __restrict__ x,
                                                          const float* __restrict__ proto,
                                                          const float* __restrict__ selfs,
                                                          const float* __restrict__ pre_max,
                                                          const int* __restrict__ pre_label,
                                                          float* apn) {
    __shared__ int lst[NQ];
    __shared__ float red[256];
    __shared__ int cnt_s;
    int c = blockIdx.x, t = threadIdx.x;
    if (t == 0) cnt_s = 0;
    __syncthreads();
    float lm = -INFINITY;
    for (int g = t; g < NQ; g += 256) {
        if (pre_label[g] == c) {
            int p = atomicAdd(&cnt_s, 1);
            lst[p] = g;
            lm = fmaxf(lm, pre_max[g]);
        }
    }
    float m = fmaxf(blk_reduce_max(lm, red), selfs[c]);   // barrier publishes lst/cnt_s
    int cnt = cnt_s;
    float ls = 0.f;
    for (int e = t; e < cnt; e += 256) ls += expf(pre_max[lst[e]] - m);
    float es = expf(selfs[c] - m);
    float Z = blk_reduce_sum(ls, red) + es;
    float a0 = es * proto[c * DD + t], a1 = 0.f, a2 = 0.f, a3 = 0.f;
    int e = 0;
    for (; e + 3 < cnt; e += 4) {
        int g0 = lst[e], g1 = lst[e + 1], g2 = lst[e + 2], g3 = lst[e + 3];
        float w0 = expf(pre_max[g0] - m), w1 = expf(pre_max[g1] - m);
        float w2 = expf(pre_max[g2] - m), w3 = expf(pre_max[g3] - m);
        a0 += w0 * x[(long)qrow(g0) * DD + t];
        a1 += w1 * x[(long)qrow(g1) * DD + t];
        a2 += w2 * x[(long)qrow(g2) * DD + t];
        a3 += w3 * x[(long)qrow(g3) * DD + t];
    }
    for (; e < cnt; e++) {
        int g0 = lst[e];
        a0 += expf(pre_max[g0] - m) * x[(long)qrow(g0) * DD + t];
    }
    float ap = ((a0 + a1) + (a2 + a3)) / Z;
    float n2 = blk_reduce_sum(ap * ap, red);
    apn[c * DD + t] = ap / sqrtf(n2);
}

// ---------- K4: bf16 MFMA coarse cosines — BATCH-BITONIC top-12 scan ----------
// (R12 verified. Unchanged.)
#define CASD(A, B) { unsigned int _x = (A), _y = (B); (A) = _x > _y ? _x : _y; (B) = _x > _y ? _y : _x; }
#define CASA(A, B) { unsigned int _x = (A), _y = (B); (A) = _x < _y ? _x : _y; (B) = _x < _y ? _y : _x; }

#define COMPUTE_TILE_L(LBUF, TILE)                                                 \
    {                                                                              \
        f32x4 accE = {2.f, 2.f, 2.f, 2.f};                                         \
        f32x4 accO = {0.f, 0.f, 0.f, 0.f};                                         \
        _Pragma("unroll")                                                          \
        for (int kc = 0; kc < 8; kc += 2) {                                        \
            short8 cfe = *(const short8*)((LBUF) + ((nn << 8) + ((((kc + 0) * 4 + qd) ^ xm) << 3))); \
            short8 cfo = *(const short8*)((LBUF) + ((nn << 8) + ((((kc + 1) * 4 + qd) ^ xm) << 3))); \
            accE = __builtin_amdgcn_mfma_f32_16x16x32_bf16(cfe, qh[kc + 0], accE, 0, 0, 0); \
            accO = __builtin_amdgcn_mfma_f32_16x16x32_bf16(cfo, qh[kc + 1], accO, 0, 0, 0); \
        }                                                                          \
        const unsigned int cb_ = (unsigned int)((TILE) * 16 + 4 * qd);             \
        unsigned int v0 = (__float_as_uint(accE[0] + accO[0]) & 0xFFFFFC00u) | (cb_ + 0); \
        unsigned int v1 = (__float_as_uint(accE[1] + accO[1]) & 0xFFFFFC00u) | (cb_ + 1); \
        unsigned int v2 = (__float_as_uint(accE[2] + accO[2]) & 0xFFFFFC00u) | (cb_ + 2); \
        unsigned int v3 = (__float_as_uint(accE[3] + accO[3]) & 0xFFFFFC00u) | (cb_ + 3); \
        /* sort batch ascending: v0<=v1<=v2<=v3 */                                 \
        CASA(v0, v1) CASA(v2, v3) CASA(v0, v2) CASA(v1, v3) CASA(v1, v2)           \
        /* split16 (valley keys[0..11]++v[0..3]); (i,i+8) for i<4 are no-ops */    \
        unsigned int t4 = keys[4], t5 = keys[5], t6 = keys[6], t7 = keys[7];       \
        unsigned int b4 = t4 < v0 ? t4 : v0; t4 = t4 > v0 ? t4 : v0;               \
        unsigned int b5 = t5 < v1 ? t5 : v1; t5 = t5 > v1 ? t5 : v1;               \
        unsigned int b6 = t6 < v2 ? t6 : v2; t6 = t6 > v2 ? t6 : v2;               \
        unsigned int b7 = t7 < v3 ? t7 : v3; t7 = t7 > v3 ? t7 : v3;               \
        /* sort top-8 [keys0..3, t4..7] desc (bitonic) */                          \
        CASD(keys[0], t4) CASD(keys[1], t5) CASD(keys[2], t6) CASD(keys[3], t7)    \
        CASD(keys[0], keys[2]) CASD(keys[1], keys[3]) CASD(t4, t6) CASD(t5, t7)    \
        CASD(keys[0], keys[1]) CASD(keys[2], keys[3]) CASD(t4, t5) CASD(t6, t7)    \
        keys[4] = t4; keys[5] = t5; keys[6] = t6; keys[7] = t7;                    \
        /* bottom-8 [keys8..11, b4..7] bitonic: top-4 via split (max only) */      \
        unsigned int B0 = keys[8]  > b4 ? keys[8]  : b4;                           \
        unsigned int B1 = keys[9]  > b5 ? keys[9]  : b5;                           \
        unsigned int B2 = keys[10] > b6 ? keys[10] : b6;                           \
        unsigned int B3 = keys[11] > b7 ? keys[11] : b7;                           \
        CASD(B0, B2) CASD(B1, B3) CASD(B0, B1) CASD(B2, B3)                        \
        keys[8] = B0; keys[9] = B1; keys[10] = B2; keys[11] = B3;                  \
    }

#define GLOAD(RA, RB, TL)                                                          \
    {                                                                              \
        const unsigned short* tb = xh + ((size_t)(col0 + (TL) * 16) << 8);         \
        RA = *(const uint4*)(tb + (G0 << 3));                                      \
        RB = *(const uint4*)(tb + (G1 << 3));                                      \
    }

#define DSWRITE(P, RA, RB)                                                         \
    {                                                                              \
        *(uint4*)((P) + (u0 << 3)) = RA;                                           \
        *(uint4*)((P) + (u1 << 3)) = RB;                                           \
    }

__global__ __launch_bounds__(256, 4) void simtopk_kernel(const unsigned short* __restrict__ xh,
                                                         int* __restrict__ topi4) {
    __shared__ uint4 smem4[2048];   // 32 KB: 2 buffers x 2 tiles; dump alias 13.3KB
    unsigned short* Tb = (unsigned short*)smem4;

    const int t = threadIdx.x;
    const int b = blockIdx.x;
    const int rb = b >> 3;          // 128 row-blocks of 64 rows
    const int ch = b & 7;           // column chunk (== XCD id under round-robin: L2-local)
    const int row0 = rb * 64;
    const int col0 = ch * 1024;

    const int wv = t >> 6;
    const int lane = t & 63;
    const int qd = lane >> 4;
    const int nn = lane & 15;
    const int xm = nn & 7;

    // staging geometry: tile = 512 x 16B units; thread handles G0=t, G1=256+t
    const int G0 = t, G1 = 256 + t;
    const int r0r = G0 >> 5, c0u = G0 & 31;
    const int u0 = r0r * 32 + (c0u ^ (r0r & 7));
    const int r1r = G1 >> 5, c1u = G1 & 31;
    const int u1 = r1r * 32 + (c1u ^ (r1r & 7));

    // Query fragments (MFMA B operand): lane holds Q[n=nn][k=kc*32+qd*8 ..+7]
    const int arow = (row0 + wv * 16 + nn) * DD;
    short8 qh[8];
    #pragma unroll
    for (int kc = 0; kc < 8; kc++)
        qh[kc] = *(const short8*)(xh + arow + kc * 32 + qd * 8);

    unsigned int keys[QK];
    #pragma unroll
    for (int s = 0; s < QK; s++) keys[s] = 0u;

    uint4 RA, RB, RC, RD;
    GLOAD(RA, RB, 0)
    GLOAD(RC, RD, 1)
    DSWRITE(Tb, RA, RB)
    DSWRITE(Tb + 4096, RC, RD)
    __syncthreads();                         // tiles 0,1 ready in buffer 0

    #pragma unroll 1
    for (int p = 0; p < 32; ++p) {
        const int cur = (p & 1) << 13;       // 0 / 8192 shorts (16KB buffers)
        if (p < 31) { GLOAD(RA, RB, 2 * p + 2) GLOAD(RC, RD, 2 * p + 3) }
        COMPUTE_TILE_L(Tb + cur, 2 * p)
        COMPUTE_TILE_L(Tb + cur + 4096, 2 * p + 1)
        if (p < 31) {
            DSWRITE(Tb + (cur ^ 8192), RA, RB)
            DSWRITE(Tb + (cur ^ 8192) + 4096, RC, RD)
        }
        __syncthreads();                     // publishes pair p+1; orders reads of pair p
    }

    // dump (wave-private region, in-order DS: no barrier) + 4-list merge.
    unsigned int* dw = (unsigned int*)smem4 + wv * 832;
    #pragma unroll
    for (int s = 0; s < QK; s++) dw[lane * 13 + s] = keys[s];
    if (lane < 16) {
        const int g = row0 + wv * 16 + lane;
        const int b0 = (lane +  0) * 13;
        const int b1 = (lane + 16) * 13;
        const int b2 = (lane + 32) * 13;
        const int b3 = (lane + 48) * 13;
        int p0 = 0, p1 = 0, p2 = 0, p3 = 0;
        for (int s = 0; s < QK; s++) {
            unsigned int v0 = (p0 < QK) ? dw[b0 + p0] : 0u;
            unsigned int v1 = (p1 < QK) ? dw[b1 + p1] : 0u;
            unsigned int v2 = (p2 < QK) ? dw[b2 + p2] : 0u;
            unsigned int v3 = (p3 < QK) ? dw[b3 + p3] : 0u;
            unsigned int bv = v0; int bw = 0;
            if (v1 > bv) { bv = v1; bw = 1; }
            if (v2 > bv) { bv = v2; bw = 2; }
            if (v3 > bv) { bv = v3; bw = 3; }
            topi4[g * CAND + ch * QK + s] = col0 + (int)(bv & 1023u);
            if (bw == 0) p0++; else if (bw == 1) p1++; else if (bw == 2) p2++; else p3++;
        }
    }
}

// ---------- K5: rescoring — 16-lane groups, coalesced, 1 DS-op/candidate ----------
// R15 lesson (coalescing is per-INSTRUCTION): per-lane private streams made
// every wave-load touch 64 distinct lines -> vmem pipe 8x cost, dur 84->168,
// VALUBusy 12.5%. Revert to coalesced loads; attack R14's real cost (6-step
// 64-lane butterfly = 18K DS-ops/CU) instead: 16 lanes per candidate, 4
// candidates per wave instruction (each group reads a contiguous 256B seg ->
// 8 lines/instr, same as R14), xor-tree offsets 8/4/2/1 stays group-local ->
// 4 DS-instr per 4 candidates = 1 DS-op/candidate (6x down). ILP 2 via two
// candidates per group per pass (3 passes x 8 cands/wave).
__global__ __launch_bounds__(256, 4) void rescore_kernel(const float* __restrict__ x,
                                                         const float* __restrict__ qInv,
                                                         const int* __restrict__ topi4,
                                                         float* __restrict__ topv,
                                                         int* __restrict__ topi) {
    __shared__ float sc[CAND];
    __shared__ int   si[CAND];
    const int g = blockIdx.x;
    const int t = threadIdx.x;
    const int lane = t & 63;
    const int w = t >> 6;            // wave's candidate group [24w, 24w+24)
    const int gr = lane >> 4;        // 16-lane group 0..3
    const int sub = lane & 15;
    const float qg = qInv[g];
    const float4* a4 = (const float4*)(x + (long)qrow(g) * DD);
    float4 aq[4];
    #pragma unroll
    for (int k = 0; k < 4; k++) aq[k] = a4[k * 16 + sub];   // query elems [k*64+sub*4..+3]
    const int cb = g * CAND + w * 24;
    #pragma unroll 1
    for (int pass = 0; pass < 3; ++pass) {
        const int c0 = pass * 8 + gr;
        const int c1 = pass * 8 + 4 + gr;
        int j0 = topi4[cb + c0]; j0 = ((unsigned)j0 < NQ) ? j0 : 0;
        int j1 = topi4[cb + c1]; j1 = ((unsigned)j1 < NQ) ? j1 : 0;
        const float4* b40 = (const float4*)(x + (long)qrow(j0) * DD);
        const float4* b41 = (const float4*)(x + (long)qrow(j1) * DD);
        float p0 = 0.f, p1 = 0.f;
        #pragma unroll
        for (int k = 0; k < 4; k++) {
            float4 b0 = b40[k * 16 + sub];
            float4 b1 = b41[k * 16 + sub];
            p0 = fmaf(aq[k].x, b0.x, p0); p0 = fmaf(aq[k].y, b0.y, p0);
            p0 = fmaf(aq[k].z, b0.z, p0); p0 = fmaf(aq[k].w, b0.w, p0);
            p1 = fmaf(aq[k].x, b1.x, p1); p1 = fmaf(aq[k].y, b1.y, p1);
            p1 = fmaf(aq[k].z, b1.z, p1); p1 = fmaf(aq[k].w, b1.w, p1);
        }
        #pragma unroll
        for (int off = 8; off > 0; off >>= 1) {
            p0 += __shfl_xor(p0, off);
            p1 += __shfl_xor(p1, off);
        }
        if (sub == 0) {
            sc[w * 24 + c0] = p0 * qInv[j0] * qg; si[w * 24 + c0] = j0;
            sc[w * 24 + c1] = p1 * qInv[j1] * qg; si[w * 24 + c1] = j1;
        }
    }
    __syncthreads();
    if (t < 64) {
        float v0 = sc[lane];
        int   i0 = si[lane];
        float v1 = -INFINITY; int i1 = 0x7fffffff;
        if (lane < CAND - 64) { v1 = sc[64 + lane]; i1 = si[64 + lane]; }
        #pragma unroll 1
        for (int s = 0; s < KNB; ++s) {
            bool sel1 = (v1 > v0) || (v1 == v0 && i1 < i0);
            float bv = sel1 ? v1 : v0;
            int   bi = sel1 ? i1 : i0;
            #pragma unroll
            for (int off = 32; off > 0; off >>= 1) {
                float ov = __shfl_xor(bv, off);
                int   oi = __shfl_xor(bi, off);
                bool take = (ov > bv) || (ov == bv && oi < bi);
                bv = take ? ov : bv;
                bi = take ? oi : bi;
            }
            if (lane == 0) { topv[g * KNB + s] = bv; topi[g * KNB + s] = bi; }
            if (i0 == bi) v0 = -INFINITY;
            if (i1 == bi) v1 = -INFINITY;
        }
    }
}

// ---------- K6: mutual-kNN softmax, adapted query, final cos sims ----------
// (R14 verified: off the top-5. Unchanged.)
__global__ __launch_bounds__(256, 8) void final_kernel(const float* __restrict__ x,
                                                       const float* __restrict__ apn,
                                                       const float* __restrict__ topv,
                                                       const int* __restrict__ topi,
                                                       const float* __restrict__ tao_raw,
                                                       float* out) {
    __shared__ float tv[KNB]; __shared__ int ti[KNB]; __shared__ float w[KNB];
    __shared__ int mutf[KNB * KNB];
    __shared__ __align__(16) float aq2[272];
    __shared__ float red4[4];
    __shared__ float part[256];
    int i = blockIdx.x, t = threadIdx.x;
    const int lane = t & 63, wv = t >> 6;
    if (t < KNB) {
        tv[t] = topv[i * KNB + t];
        int j = topi[i * KNB + t];
        ti[t] = ((unsigned)j < NQ) ? j : 0;
    }
    __syncthreads();
    if (t < KNB * KNB) {                        // parallel mutual: 100 loads in flight
        const int s = t / KNB, u = t - s * KNB;
        mutf[t] = (topi[ti[s] * KNB + u] == i) ? 1 : 0;
    }
    __syncthreads();
    if (t < 16) {                               // OR-reduce flags + wave softmax
        float val = -INFINITY;
        if (t < KNB) {
            const int* mf = &mutf[t * KNB];
            int any = mf[0] | mf[1] | mf[2] | mf[3] | mf[4]
                    | mf[5] | mf[6] | mf[7] | mf[8] | mf[9];
            val = any ? tv[t] : -INFINITY;
        }
        float m = val;
        #pragma unroll
        for (int off = 8; off > 0; off >>= 1) m = fmaxf(m, __shfl_xor(m, off));
        float e = (t < KNB) ? expf(val - m) : 0.f;
        float Z = e;
        #pragma unroll
        for (int off = 8; off > 0; off >>= 1) Z += __shfl_xor(Z, off);
        if (t < KNB) w[t] = e / Z;
    }
    __syncthreads();
    // preload weights + indices to registers, then batch all 10 row gathers
    float wr[KNB]; int tr[KNB];
    #pragma unroll
    for (int s = 0; s < KNB; s++) { wr[s] = w[s]; tr[s] = ti[s]; }
    float xv[KNB];
    #pragma unroll
    for (int s = 0; s < KNB; s++) xv[s] = x[(long)qrow(tr[s]) * DD + t];
    float a = 0.f;
    #pragma unroll
    for (int s = 0; s < KNB; s++) a += wr[s] * xv[s];
    aq2[t + (t >> 6) * 4] = a;
    float v2 = a * a;
    #pragma unroll
    for (int off = 32; off > 0; off >>= 1) v2 += __shfl_xor(v2, off);
    if (lane == 0) red4[wv] = v2;
    __syncthreads();                            // publishes aq2 + red4
    float n2 = red4[0] + red4[1] + red4[2] + red4[3];
    float inv = 1.f / sqrtf(n2);
    int c = t >> 2, tl = t & 3;
    float sdot = 0.f;
    const float* aqb = aq2 + tl * 68;
    const float4* ap4 = (const float4*)(apn + c * DD + tl * 64);
    #pragma unroll
    for (int u4 = 0; u4 < 16; u4++) {
        float4 av = *(const float4*)(aqb + u4 * 4);
        float4 pv = ap4[u4];
        sdot += av.x * pv.x; sdot += av.y * pv.y; sdot += av.z * pv.z; sdot += av.w * pv.w;
    }
    part[t] = sdot; __syncthreads();
    if (tl == 0) {
        float sv = part[t] + part[t + 1] + part[t + 2] + part[t + 3];
        out[i * NCLS + c] = tao_raw[0] * sv * inv;
    }
}

extern "C" void kernel_launch(void* const* d_in, const int* in_sizes, int n_in,
                              void* d_out, int out_size, void* d_ws, size_t ws_size,
                              hipStream_t stream) {
    (void)in_sizes; (void)n_in; (void)out_size;
    const float* x   = (const float*)d_in[0];
    const float* tao = (const float*)d_in[1];
    float* out = (float*)d_out;

    char* ws = (char*)d_ws;
    size_t off = 0;
    auto carve = [&](size_t bytes) {
        void* p = ws + off;
        off = (off + bytes + 255) & ~(size_t)255;
        return p;
    };
    float*          proto   = (float*)carve(NCLS * DD * 4);
    float*          pn      = (float*)carve(NCLS * DD * 4);
    float*          selfs   = (float*)carve(NCLS * 4);
    float*          qInv    = (float*)carve(NQ * 4);
    float*          pre_max = (float*)carve(NQ * 4);
    int*            pre_lab = (int*)carve(NQ * 4);
    float*          apn     = (float*)carve(NCLS * DD * 4);
    unsigned short* xh      = (unsigned short*)carve((size_t)NQ * DD * 2);
    int*            topi4   = (int*)carve((size_t)NQ * CAND * 4);
    float*          topv    = (float*)carve((size_t)NQ * KNB * 4);
    int*            topi    = (int*)carve((size_t)NQ * KNB * 4);
    if (off > ws_size) return;

    proto_kernel<<<NCLS, 256, 0, stream>>>(x, proto, pn, selfs);
    presim_kernel<<<NQ, 256, 0, stream>>>(x, pn, xh, qInv, pre_max, pre_lab);
    adapt_proto_kernel<<<NCLS, 256, 0, stream>>>(x, proto, selfs, pre_max, pre_lab, apn);
    simtopk_kernel<<<NQ / 64 * NCH, 256, 0, stream>>>(xh, topi4);
    rescore_kernel<<<NQ, 256, 0, stream>>>(x, qInv, topi4, topv, topi);
    final_kernel<<<NQ, 256, 0, stream>>>(x, apn, topv, topi, tao, out);
}

// Round 17
// 276.968 us; speedup vs baseline: 1.6385x; 1.2806x over previous
//
#include <hip/hip_runtime.h>
#include <math.h>

#define NCLS 64
#define KS 5
#define DD 256
#define NQ 8192   // NCLS*128
#define KNB 10
#define QK 12     // per-chunk candidate list depth (need >=10 for exact containment)
#define NCH 8     // column chunks per row (1024 cols each)
#define CAND 96   // NCH * QK

typedef __attribute__((ext_vector_type(8))) short short8;   // 8 bf16 bit-patterns (4 VGPRs)
typedef __attribute__((ext_vector_type(4))) float f32x4;    // MFMA C/D frag

// row index in x (fp32 row units) of query g
__device__ __forceinline__ int qrow(int g) { return (g >> 7) * 133 + KS + (g & 127); }

__device__ __forceinline__ unsigned short bf16_rne(float f) {
    unsigned int u = __float_as_uint(f);
    u += 0x7fffu + ((u >> 16) & 1u);
    return (unsigned short)(u >> 16);
}

__device__ __forceinline__ float blk_reduce_sum(float v, float* red) {
    int t = threadIdx.x;
    red[t] = v; __syncthreads();
    for (int off = 128; off > 0; off >>= 1) {
        if (t < off) red[t] += red[t + off];
        __syncthreads();
    }
    float r = red[0];
    __syncthreads();
    return r;
}

__device__ __forceinline__ float blk_reduce_max(float v, float* red) {
    int t = threadIdx.x;
    red[t] = v; __syncthreads();
    for (int off = 128; off > 0; off >>= 1) {
        if (t < off) red[t] = fmaxf(red[t], red[t + off]);
        __syncthreads();
    }
    float r = red[0];
    __syncthreads();
    return r;
}

// ---------- K1: proto, pn, self_sim ----------
__global__ __launch_bounds__(256) void proto_kernel(const float* __restrict__ x,
                                                    float* proto, float* pn, float* selfs) {
    __shared__ float red[256];
    int c = blockIdx.x, t = threadIdx.x;
    float s = 0.f;
    for (int j = 0; j < KS; j++) s += x[(long)(c * 133 + j) * DD + t];
    float p = s / 5.0f;
    proto[c * DD + t] = p;
    float n2 = blk_reduce_sum(p * p, red);
    float pv = p / sqrtf(n2);
    pn[c * DD + t] = pv;
    float ss = blk_reduce_sum(pv * pv, red);
    if (t == 0) selfs[c] = ss;
}

// ---------- K2: FUSED split + pre_sim argmax ----------
// R16: pn read was 64 distinct lines per wave-instruction (c*1024B + tl*256B
// spread). Reshaped lane->element map: lane (c,tl) reads pn[c*DD+u4*16+tl*4]
// -> 4-lane group = one contiguous 64B line -> 16 lines/instr (4x less TA).
// qs2 side becomes wave-broadcast. Same 256-elem dot, reassociated only.
__global__ __launch_bounds__(256) void presim_kernel(const float* __restrict__ x,
                                                     const float* __restrict__ pn,
                                                     unsigned short* __restrict__ xh,
                                                     float* __restrict__ qInv,
                                                     float* pre_max, int* pre_label) {
    __shared__ __align__(16) float qs2[272];
    __shared__ float red4[4];
    __shared__ float part[256];
    __shared__ float sims[64];
    int g = blockIdx.x, t = threadIdx.x;
    const int lane = t & 63, wv = t >> 6;
    float v = x[(long)qrow(g) * DD + t];
    qs2[t + (t >> 6) * 4] = v;
    float v2 = v * v;
    #pragma unroll
    for (int off = 32; off > 0; off >>= 1) v2 += __shfl_xor(v2, off);
    if (lane == 0) red4[wv] = v2;
    __syncthreads();                               // publishes qs2 + red4
    float n2 = red4[0] + red4[1] + red4[2] + red4[3];
    float inv = 1.f / sqrtf(n2);
    xh[g * DD + t] = bf16_rne(v * inv);
    if (t == 0) qInv[g] = inv;
    int c = t >> 2, tl = t & 3;
    float s = 0.f;
    #pragma unroll
    for (int u4 = 0; u4 < 16; u4++) {
        float4 a = *(const float4*)(qs2 + u4 * 16 + (u4 >> 2) * 4 + tl * 4);
        float4 b = *(const float4*)(pn + c * DD + u4 * 16 + tl * 4);
        s += a.x * b.x; s += a.y * b.y; s += a.z * b.z; s += a.w * b.w;
    }
    part[t] = s; __syncthreads();
    if (tl == 0) sims[c] = part[t] + part[t + 1] + part[t + 2] + part[t + 3];
    __syncthreads();
    if (t < 64) {
        float bv = sims[t]; int bi = t;
        #pragma unroll
        for (int off = 32; off > 0; off >>= 1) {
            float ov = __shfl_xor(bv, off);
            int   oi = __shfl_xor(bi, off);
            bool take = (ov > bv) || (ov == bv && oi < bi);
            bv = take ? ov : bv;
            bi = take ? oi : bi;
        }
        if (t == 0) { pre_max[g] = bv * inv; pre_label[g] = bi; }
    }
}

// ---------- K3: adapted prototypes — LDS-compacted member list ----------
__global__ __launch_bounds__(256) void adapt_proto_kernel(const float* __restrict__ x,
                                                          const float* __restrict__ proto,
                                                          const float* __restrict__ selfs,
                                                          const float* __restrict__ pre_max,
                                                          const int* __restrict__ pre_label,
                                                          float* apn) {
    __shared__ int lst[NQ];
    __shared__ float red[256];
    __shared__ int cnt_s;
    int c = blockIdx.x, t = threadIdx.x;
    if (t == 0) cnt_s = 0;
    __syncthreads();
    float lm = -INFINITY;
    for (int g = t; g < NQ; g += 256) {
        if (pre_label[g] == c) {
            int p = atomicAdd(&cnt_s, 1);
            lst[p] = g;
            lm = fmaxf(lm, pre_max[g]);
        }
    }
    float m = fmaxf(blk_reduce_max(lm, red), selfs[c]);   // barrier publishes lst/cnt_s
    int cnt = cnt_s;
    float ls = 0.f;
    for (int e = t; e < cnt; e += 256) ls += expf(pre_max[lst[e]] - m);
    float es = expf(selfs[c] - m);
    float Z = blk_reduce_sum(ls, red) + es;
    float a0 = es * proto[c * DD + t], a1 = 0.f, a2 = 0.f, a3 = 0.f;
    int e = 0;
    for (; e + 3 < cnt; e += 4) {
        int g0 = lst[e], g1 = lst[e + 1], g2 = lst[e + 2], g3 = lst[e + 3];
        float w0 = expf(pre_max[g0] - m), w1 = expf(pre_max[g1] - m);
        float w2 = expf(pre_max[g2] - m), w3 = expf(pre_max[g3] - m);
        a0 += w0 * x[(long)qrow(g0) * DD + t];
        a1 += w1 * x[(long)qrow(g1) * DD + t];
        a2 += w2 * x[(long)qrow(g2) * DD + t];
        a3 += w3 * x[(long)qrow(g3) * DD + t];
    }
    for (; e < cnt; e++) {
        int g0 = lst[e];
        a0 += expf(pre_max[g0] - m) * x[(long)qrow(g0) * DD + t];
    }
    float ap = ((a0 + a1) + (a2 + a3)) / Z;
    float n2 = blk_reduce_sum(ap * ap, red);
    apn[c * DD + t] = ap / sqrtf(n2);
}

// ---------- K4: bf16 MFMA coarse cosines — BATCH-BITONIC top-12 scan ----------
// (R12 verified. Unchanged.)
#define CASD(A, B) { unsigned int _x = (A), _y = (B); (A) = _x > _y ? _x : _y; (B) = _x > _y ? _y : _x; }
#define CASA(A, B) { unsigned int _x = (A), _y = (B); (A) = _x < _y ? _x : _y; (B) = _x < _y ? _y : _x; }

#define COMPUTE_TILE_L(LBUF, TILE)                                                 \
    {                                                                              \
        f32x4 accE = {2.f, 2.f, 2.f, 2.f};                                         \
        f32x4 accO = {0.f, 0.f, 0.f, 0.f};                                         \
        _Pragma("unroll")                                                          \
        for (int kc = 0; kc < 8; kc += 2) {                                        \
            short8 cfe = *(const short8*)((LBUF) + ((nn << 8) + ((((kc + 0) * 4 + qd) ^ xm) << 3))); \
            short8 cfo = *(const short8*)((LBUF) + ((nn << 8) + ((((kc + 1) * 4 + qd) ^ xm) << 3))); \
            accE = __builtin_amdgcn_mfma_f32_16x16x32_bf16(cfe, qh[kc + 0], accE, 0, 0, 0); \
            accO = __builtin_amdgcn_mfma_f32_16x16x32_bf16(cfo, qh[kc + 1], accO, 0, 0, 0); \
        }                                                                          \
        const unsigned int cb_ = (unsigned int)((TILE) * 16 + 4 * qd);             \
        unsigned int v0 = (__float_as_uint(accE[0] + accO[0]) & 0xFFFFFC00u) | (cb_ + 0); \
        unsigned int v1 = (__float_as_uint(accE[1] + accO[1]) & 0xFFFFFC00u) | (cb_ + 1); \
        unsigned int v2 = (__float_as_uint(accE[2] + accO[2]) & 0xFFFFFC00u) | (cb_ + 2); \
        unsigned int v3 = (__float_as_uint(accE[3] + accO[3]) & 0xFFFFFC00u) | (cb_ + 3); \
        /* sort batch ascending: v0<=v1<=v2<=v3 */                                 \
        CASA(v0, v1) CASA(v2, v3) CASA(v0, v2) CASA(v1, v3) CASA(v1, v2)           \
        /* split16 (valley keys[0..11]++v[0..3]); (i,i+8) for i<4 are no-ops */    \
        unsigned int t4 = keys[4], t5 = keys[5], t6 = keys[6], t7 = keys[7];       \
        unsigned int b4 = t4 < v0 ? t4 : v0; t4 = t4 > v0 ? t4 : v0;               \
        unsigned int b5 = t5 < v1 ? t5 : v1; t5 = t5 > v1 ? t5 : v1;               \
        unsigned int b6 = t6 < v2 ? t6 : v2; t6 = t6 > v2 ? t6 : v2;               \
        unsigned int b7 = t7 < v3 ? t7 : v3; t7 = t7 > v3 ? t7 : v3;               \
        /* sort top-8 [keys0..3, t4..7] desc (bitonic) */                          \
        CASD(keys[0], t4) CASD(keys[1], t5) CASD(keys[2], t6) CASD(keys[3], t7)    \
        CASD(keys[0], keys[2]) CASD(keys[1], keys[3]) CASD(t4, t6) CASD(t5, t7)    \
        CASD(keys[0], keys[1]) CASD(keys[2], keys[3]) CASD(t4, t5) CASD(t6, t7)    \
        keys[4] = t4; keys[5] = t5; keys[6] = t6; keys[7] = t7;                    \
        /* bottom-8 [keys8..11, b4..7] bitonic: top-4 via split (max only) */      \
        unsigned int B0 = keys[8]  > b4 ? keys[8]  : b4;                           \
        unsigned int B1 = keys[9]  > b5 ? keys[9]  : b5;                           \
        unsigned int B2 = keys[10] > b6 ? keys[10] : b6;                           \
        unsigned int B3 = keys[11] > b7 ? keys[11] : b7;                           \
        CASD(B0, B2) CASD(B1, B3) CASD(B0, B1) CASD(B2, B3)                        \
        keys[8] = B0; keys[9] = B1; keys[10] = B2; keys[11] = B3;                  \
    }

#define GLOAD(RA, RB, TL)                                                          \
    {                                                                              \
        const unsigned short* tb = xh + ((size_t)(col0 + (TL) * 16) << 8);         \
        RA = *(const uint4*)(tb + (G0 << 3));                                      \
        RB = *(const uint4*)(tb + (G1 << 3));                                      \
    }

#define DSWRITE(P, RA, RB)                                                         \
    {                                                                              \
        *(uint4*)((P) + (u0 << 3)) = RA;                                           \
        *(uint4*)((P) + (u1 << 3)) = RB;                                           \
    }

__global__ __launch_bounds__(256, 4) void simtopk_kernel(const unsigned short* __restrict__ xh,
                                                         int* __restrict__ topi4) {
    __shared__ uint4 smem4[2048];   // 32 KB: 2 buffers x 2 tiles; dump alias 13.3KB
    unsigned short* Tb = (unsigned short*)smem4;

    const int t = threadIdx.x;
    const int b = blockIdx.x;
    const int rb = b >> 3;          // 128 row-blocks of 64 rows
    const int ch = b & 7;           // column chunk (== XCD id under round-robin: L2-local)
    const int row0 = rb * 64;
    const int col0 = ch * 1024;

    const int wv = t >> 6;
    const int lane = t & 63;
    const int qd = lane >> 4;
    const int nn = lane & 15;
    const int xm = nn & 7;

    // staging geometry: tile = 512 x 16B units; thread handles G0=t, G1=256+t
    const int G0 = t, G1 = 256 + t;
    const int r0r = G0 >> 5, c0u = G0 & 31;
    const int u0 = r0r * 32 + (c0u ^ (r0r & 7));
    const int r1r = G1 >> 5, c1u = G1 & 31;
    const int u1 = r1r * 32 + (c1u ^ (r1r & 7));

    // Query fragments (MFMA B operand): lane holds Q[n=nn][k=kc*32+qd*8 ..+7]
    const int arow = (row0 + wv * 16 + nn) * DD;
    short8 qh[8];
    #pragma unroll
    for (int kc = 0; kc < 8; kc++)
        qh[kc] = *(const short8*)(xh + arow + kc * 32 + qd * 8);

    unsigned int keys[QK];
    #pragma unroll
    for (int s = 0; s < QK; s++) keys[s] = 0u;

    uint4 RA, RB, RC, RD;
    GLOAD(RA, RB, 0)
    GLOAD(RC, RD, 1)
    DSWRITE(Tb, RA, RB)
    DSWRITE(Tb + 4096, RC, RD)
    __syncthreads();                         // tiles 0,1 ready in buffer 0

    #pragma unroll 1
    for (int p = 0; p < 32; ++p) {
        const int cur = (p & 1) << 13;       // 0 / 8192 shorts (16KB buffers)
        if (p < 31) { GLOAD(RA, RB, 2 * p + 2) GLOAD(RC, RD, 2 * p + 3) }
        COMPUTE_TILE_L(Tb + cur, 2 * p)
        COMPUTE_TILE_L(Tb + cur + 4096, 2 * p + 1)
        if (p < 31) {
            DSWRITE(Tb + (cur ^ 8192), RA, RB)
            DSWRITE(Tb + (cur ^ 8192) + 4096, RC, RD)
        }
        __syncthreads();                     // publishes pair p+1; orders reads of pair p
    }

    // dump (wave-private region, in-order DS: no barrier) + 4-list merge.
    unsigned int* dw = (unsigned int*)smem4 + wv * 832;
    #pragma unroll
    for (int s = 0; s < QK; s++) dw[lane * 13 + s] = keys[s];
    if (lane < 16) {
        const int g = row0 + wv * 16 + lane;
        const int b0 = (lane +  0) * 13;
        const int b1 = (lane + 16) * 13;
        const int b2 = (lane + 32) * 13;
        const int b3 = (lane + 48) * 13;
        int p0 = 0, p1 = 0, p2 = 0, p3 = 0;
        for (int s = 0; s < QK; s++) {
            unsigned int v0 = (p0 < QK) ? dw[b0 + p0] : 0u;
            unsigned int v1 = (p1 < QK) ? dw[b1 + p1] : 0u;
            unsigned int v2 = (p2 < QK) ? dw[b2 + p2] : 0u;
            unsigned int v3 = (p3 < QK) ? dw[b3 + p3] : 0u;
            unsigned int bv = v0; int bw = 0;
            if (v1 > bv) { bv = v1; bw = 1; }
            if (v2 > bv) { bv = v2; bw = 2; }
            if (v3 > bv) { bv = v3; bw = 3; }
            topi4[g * CAND + ch * QK + s] = col0 + (int)(bv & 1023u);
            if (bw == 0) p0++; else if (bw == 1) p1++; else if (bw == 2) p2++; else p3++;
        }
    }
}

// ---------- K5: rescoring — 16-lane groups, coalesced, 1 DS-op/candidate ----------
// (R16 verified: off the top-5. Unchanged.)
__global__ __launch_bounds__(256, 4) void rescore_kernel(const float* __restrict__ x,
                                                         const float* __restrict__ qInv,
                                                         const int* __restrict__ topi4,
                                                         float* __restrict__ topv,
                                                         int* __restrict__ topi) {
    __shared__ float sc[CAND];
    __shared__ int   si[CAND];
    const int g = blockIdx.x;
    const int t = threadIdx.x;
    const int lane = t & 63;
    const int w = t >> 6;            // wave's candidate group [24w, 24w+24)
    const int gr = lane >> 4;        // 16-lane group 0..3
    const int sub = lane & 15;
    const float qg = qInv[g];
    const float4* a4 = (const float4*)(x + (long)qrow(g) * DD);
    float4 aq[4];
    #pragma unroll
    for (int k = 0; k < 4; k++) aq[k] = a4[k * 16 + sub];   // query elems [k*64+sub*4..+3]
    const int cb = g * CAND + w * 24;
    #pragma unroll 1
    for (int pass = 0; pass < 3; ++pass) {
        const int c0 = pass * 8 + gr;
        const int c1 = pass * 8 + 4 + gr;
        int j0 = topi4[cb + c0]; j0 = ((unsigned)j0 < NQ) ? j0 : 0;
        int j1 = topi4[cb + c1]; j1 = ((unsigned)j1 < NQ) ? j1 : 0;
        const float4* b40 = (const float4*)(x + (long)qrow(j0) * DD);
        const float4* b41 = (const float4*)(x + (long)qrow(j1) * DD);
        float p0 = 0.f, p1 = 0.f;
        #pragma unroll
        for (int k = 0; k < 4; k++) {
            float4 b0 = b40[k * 16 + sub];
            float4 b1 = b41[k * 16 + sub];
            p0 = fmaf(aq[k].x, b0.x, p0); p0 = fmaf(aq[k].y, b0.y, p0);
            p0 = fmaf(aq[k].z, b0.z, p0); p0 = fmaf(aq[k].w, b0.w, p0);
            p1 = fmaf(aq[k].x, b1.x, p1); p1 = fmaf(aq[k].y, b1.y, p1);
            p1 = fmaf(aq[k].z, b1.z, p1); p1 = fmaf(aq[k].w, b1.w, p1);
        }
        #pragma unroll
        for (int off = 8; off > 0; off >>= 1) {
            p0 += __shfl_xor(p0, off);
            p1 += __shfl_xor(p1, off);
        }
        if (sub == 0) {
            sc[w * 24 + c0] = p0 * qInv[j0] * qg; si[w * 24 + c0] = j0;
            sc[w * 24 + c1] = p1 * qInv[j1] * qg; si[w * 24 + c1] = j1;
        }
    }
    __syncthreads();
    if (t < 64) {
        float v0 = sc[lane];
        int   i0 = si[lane];
        float v1 = -INFINITY; int i1 = 0x7fffffff;
        if (lane < CAND - 64) { v1 = sc[64 + lane]; i1 = si[64 + lane]; }
        #pragma unroll 1
        for (int s = 0; s < KNB; ++s) {
            bool sel1 = (v1 > v0) || (v1 == v0 && i1 < i0);
            float bv = sel1 ? v1 : v0;
            int   bi = sel1 ? i1 : i0;
            #pragma unroll
            for (int off = 32; off > 0; off >>= 1) {
                float ov = __shfl_xor(bv, off);
                int   oi = __shfl_xor(bi, off);
                bool take = (ov > bv) || (ov == bv && oi < bi);
                bv = take ? ov : bv;
                bi = take ? oi : bi;
            }
            if (lane == 0) { topv[g * KNB + s] = bv; topi[g * KNB + s] = bi; }
            if (i0 == bi) v0 = -INFINITY;
            if (i1 == bi) v1 = -INFINITY;
        }
    }
}

// ---------- K6: mutual-kNN softmax, adapted query, final cos sims ----------
// R16 counters: 75.6us, VALUBusy 14.7% -> the sdot read apn[c*DD+tl*64+...]
// touched 64 distinct lines per wave-instruction (131K line-touches/CU ~=
// the whole dispatch). Reshaped lane->element map (same as presim): lane
// (c,tl) accumulates apn[c*DD + u4*16 + tl*4 ..+3] -> 16 lines/instr (4x).
// aq2 side becomes wave-broadcast. Same dot, reassociated.
__global__ __launch_bounds__(256, 8) void final_kernel(const float* __restrict__ x,
                                                       const float* __restrict__ apn,
                                                       const float* __restrict__ topv,
                                                       const int* __restrict__ topi,
                                                       const float* __restrict__ tao_raw,
                                                       float* out) {
    __shared__ float tv[KNB]; __shared__ int ti[KNB]; __shared__ float w[KNB];
    __shared__ int mutf[KNB * KNB];
    __shared__ __align__(16) float aq2[272];
    __shared__ float red4[4];
    __shared__ float part[256];
    int i = blockIdx.x, t = threadIdx.x;
    const int lane = t & 63, wv = t >> 6;
    if (t < KNB) {
        tv[t] = topv[i * KNB + t];
        int j = topi[i * KNB + t];
        ti[t] = ((unsigned)j < NQ) ? j : 0;
    }
    __syncthreads();
    if (t < KNB * KNB) {                        // parallel mutual: 100 loads in flight
        const int s = t / KNB, u = t - s * KNB;
        mutf[t] = (topi[ti[s] * KNB + u] == i) ? 1 : 0;
    }
    __syncthreads();
    if (t < 16) {                               // OR-reduce flags + wave softmax
        float val = -INFINITY;
        if (t < KNB) {
            const int* mf = &mutf[t * KNB];
            int any = mf[0] | mf[1] | mf[2] | mf[3] | mf[4]
                    | mf[5] | mf[6] | mf[7] | mf[8] | mf[9];
            val = any ? tv[t] : -INFINITY;
        }
        float m = val;
        #pragma unroll
        for (int off = 8; off > 0; off >>= 1) m = fmaxf(m, __shfl_xor(m, off));
        float e = (t < KNB) ? expf(val - m) : 0.f;
        float Z = e;
        #pragma unroll
        for (int off = 8; off > 0; off >>= 1) Z += __shfl_xor(Z, off);
        if (t < KNB) w[t] = e / Z;
    }
    __syncthreads();
    // preload weights + indices to registers, then batch all 10 row gathers
    float wr[KNB]; int tr[KNB];
    #pragma unroll
    for (int s = 0; s < KNB; s++) { wr[s] = w[s]; tr[s] = ti[s]; }
    float xv[KNB];
    #pragma unroll
    for (int s = 0; s < KNB; s++) xv[s] = x[(long)qrow(tr[s]) * DD + t];
    float a = 0.f;
    #pragma unroll
    for (int s = 0; s < KNB; s++) a += wr[s] * xv[s];
    aq2[t + (t >> 6) * 4] = a;
    float v2 = a * a;
    #pragma unroll
    for (int off = 32; off > 0; off >>= 1) v2 += __shfl_xor(v2, off);
    if (lane == 0) red4[wv] = v2;
    __syncthreads();                            // publishes aq2 + red4
    float n2 = red4[0] + red4[1] + red4[2] + red4[3];
    float inv = 1.f / sqrtf(n2);
    int c = t >> 2, tl = t & 3;
    float sdot = 0.f;
    #pragma unroll
    for (int u4 = 0; u4 < 16; u4++) {
        float4 av = *(const float4*)(aq2 + u4 * 16 + (u4 >> 2) * 4 + tl * 4);
        float4 pv = *(const float4*)(apn + c * DD + u4 * 16 + tl * 4);
        sdot += av.x * pv.x; sdot += av.y * pv.y; sdot += av.z * pv.z; sdot += av.w * pv.w;
    }
    part[t] = sdot; __syncthreads();
    if (tl == 0) {
        float sv = part[t] + part[t + 1] + part[t + 2] + part[t + 3];
        out[i * NCLS + c] = tao_raw[0] * sv * inv;
    }
}

extern "C" void kernel_launch(void* const* d_in, const int* in_sizes, int n_in,
                              void* d_out, int out_size, void* d_ws, size_t ws_size,
                              hipStream_t stream) {
    (void)in_sizes; (void)n_in; (void)out_size;
    const float* x   = (const float*)d_in[0];
    const float* tao = (const float*)d_in[1];
    float* out = (float*)d_out;

    char* ws = (char*)d_ws;
    size_t off = 0;
    auto carve = [&](size_t bytes) {
        void* p = ws + off;
        off = (off + bytes + 255) & ~(size_t)255;
        return p;
    };
    float*          proto   = (float*)carve(NCLS * DD * 4);
    float*          pn      = (float*)carve(NCLS * DD * 4);
    float*          selfs   = (float*)carve(NCLS * 4);
    float*          qInv    = (float*)carve(NQ * 4);
    float*          pre_max = (float*)carve(NQ * 4);
    int*            pre_lab = (int*)carve(NQ * 4);
    float*          apn     = (float*)carve(NCLS * DD * 4);
    unsigned short* xh      = (unsigned short*)carve((size_t)NQ * DD * 2);
    int*            topi4   = (int*)carve((size_t)NQ * CAND * 4);
    float*          topv    = (float*)carve((size_t)NQ * KNB * 4);
    int*            topi    = (int*)carve((size_t)NQ * KNB * 4);
    if (off > ws_size) return;

    proto_kernel<<<NCLS, 256, 0, stream>>>(x, proto, pn, selfs);
    presim_kernel<<<NQ, 256, 0, stream>>>(x, pn, xh, qInv, pre_max, pre_lab);
    adapt_proto_kernel<<<NCLS, 256, 0, stream>>>(x, proto, selfs, pre_max, pre_lab, apn);
    simtopk_kernel<<<NQ / 64 * NCH, 256, 0, stream>>>(xh, topi4);
    rescore_kernel<<<NQ, 256, 0, stream>>>(x, qInv, topi4, topv, topi);
    final_kernel<<<NQ, 256, 0, stream>>>(x, apn, topv, topi, tao, out);
}

// Round 18
// 261.848 us; speedup vs baseline: 1.7332x; 1.0577x over previous
//
#include <hip/hip_runtime.h>
#include <math.h>

#define NCLS 64
#define KS 5
#define DD 256
#define NQ 8192   // NCLS*128
#define KNB 10
#define QK 12     // per-chunk candidate list depth (need >=10 for exact containment)
#define NCH 8     // column chunks per row (1024 cols each)
#define CAND 96   // NCH * QK

typedef __attribute__((ext_vector_type(8))) short short8;   // 8 bf16 bit-patterns (4 VGPRs)
typedef __attribute__((ext_vector_type(4))) float f32x4;    // MFMA C/D frag

// row index in x (fp32 row units) of query g
__device__ __forceinline__ int qrow(int g) { return (g >> 7) * 133 + KS + (g & 127); }

__device__ __forceinline__ unsigned short bf16_rne(float f) {
    unsigned int u = __float_as_uint(f);
    u += 0x7fffu + ((u >> 16) & 1u);
    return (unsigned short)(u >> 16);
}

__device__ __forceinline__ float blk_reduce_sum(float v, float* red) {
    int t = threadIdx.x;
    red[t] = v; __syncthreads();
    for (int off = 128; off > 0; off >>= 1) {
        if (t < off) red[t] += red[t + off];
        __syncthreads();
    }
    float r = red[0];
    __syncthreads();
    return r;
}

__device__ __forceinline__ float blk_reduce_max(float v, float* red) {
    int t = threadIdx.x;
    red[t] = v; __syncthreads();
    for (int off = 128; off > 0; off >>= 1) {
        if (t < off) red[t] = fmaxf(red[t], red[t + off]);
        __syncthreads();
    }
    float r = red[0];
    __syncthreads();
    return r;
}

// ---------- K1: proto, pn, self_sim ----------
__global__ __launch_bounds__(256) void proto_kernel(const float* __restrict__ x,
                                                    float* proto, float* pn, float* selfs) {
    __shared__ float red[256];
    int c = blockIdx.x, t = threadIdx.x;
    float s = 0.f;
    for (int j = 0; j < KS; j++) s += x[(long)(c * 133 + j) * DD + t];
    float p = s / 5.0f;
    proto[c * DD + t] = p;
    float n2 = blk_reduce_sum(p * p, red);
    float pv = p / sqrtf(n2);
    pn[c * DD + t] = pv;
    float ss = blk_reduce_sum(pv * pv, red);
    if (t == 0) selfs[c] = ss;
}

// ---------- K2: FUSED split + pre_sim argmax (R17 coalesced reshape) ----------
__global__ __launch_bounds__(256) void presim_kernel(const float* __restrict__ x,
                                                     const float* __restrict__ pn,
                                                     unsigned short* __restrict__ xh,
                                                     float* __restrict__ qInv,
                                                     float* pre_max, int* pre_label) {
    __shared__ __align__(16) float qs2[272];
    __shared__ float red4[4];
    __shared__ float part[256];
    __shared__ float sims[64];
    int g = blockIdx.x, t = threadIdx.x;
    const int lane = t & 63, wv = t >> 6;
    float v = x[(long)qrow(g) * DD + t];
    qs2[t + (t >> 6) * 4] = v;
    float v2 = v * v;
    #pragma unroll
    for (int off = 32; off > 0; off >>= 1) v2 += __shfl_xor(v2, off);
    if (lane == 0) red4[wv] = v2;
    __syncthreads();                               // publishes qs2 + red4
    float n2 = red4[0] + red4[1] + red4[2] + red4[3];
    float inv = 1.f / sqrtf(n2);
    xh[g * DD + t] = bf16_rne(v * inv);
    if (t == 0) qInv[g] = inv;
    int c = t >> 2, tl = t & 3;
    float s = 0.f;
    #pragma unroll
    for (int u4 = 0; u4 < 16; u4++) {
        float4 a = *(const float4*)(qs2 + u4 * 16 + (u4 >> 2) * 4 + tl * 4);
        float4 b = *(const float4*)(pn + c * DD + u4 * 16 + tl * 4);
        s += a.x * b.x; s += a.y * b.y; s += a.z * b.z; s += a.w * b.w;
    }
    part[t] = s; __syncthreads();
    if (tl == 0) sims[c] = part[t] + part[t + 1] + part[t + 2] + part[t + 3];
    __syncthreads();
    if (t < 64) {
        float bv = sims[t]; int bi = t;
        #pragma unroll
        for (int off = 32; off > 0; off >>= 1) {
            float ov = __shfl_xor(bv, off);
            int   oi = __shfl_xor(bi, off);
            bool take = (ov > bv) || (ov == bv && oi < bi);
            bv = take ? ov : bv;
            bi = take ? oi : bi;
        }
        if (t == 0) { pre_max[g] = bv * inv; pre_label[g] = bi; }
    }
}

// ---------- K3a: adapted prototypes, phase A — per-(class,quarter) partials ----------
// R17: adapt_proto ran 64 blocks = 64/256 CUs (75% of chip idle). Split: block
// (c,qq) scans its 2048-label quarter, compacts members, computes LOCAL
// softmax partials (m_q, S_q = sum exp(v-m_q), A_q = sum exp(v-m_q)*x).
// Empty quarter -> m_q = -inf, S_q = A_q = 0; combine uses expf(-inf)=0.
__global__ __launch_bounds__(256) void adapt_part_kernel(const float* __restrict__ x,
                                                         const float* __restrict__ pre_max,
                                                         const int* __restrict__ pre_label,
                                                         float* __restrict__ pm_q,
                                                         float* __restrict__ ps_q,
                                                         float* __restrict__ pa_q) {
    __shared__ int lst[2048];
    __shared__ float red[256];
    __shared__ int cnt_s;
    const int b = blockIdx.x;
    const int c = b >> 2;
    const int g0 = (b & 3) * 2048;
    const int t = threadIdx.x;
    if (t == 0) cnt_s = 0;
    __syncthreads();
    float lm = -INFINITY;
    for (int g = g0 + t; g < g0 + 2048; g += 256) {
        if (pre_label[g] == c) {
            int p = atomicAdd(&cnt_s, 1);
            lst[p] = g;
            lm = fmaxf(lm, pre_max[g]);
        }
    }
    float m = blk_reduce_max(lm, red);   // barrier publishes lst/cnt_s
    int cnt = cnt_s;
    float ls = 0.f;
    for (int e = t; e < cnt; e += 256) ls += expf(pre_max[lst[e]] - m);
    float S = blk_reduce_sum(ls, red);
    float a0 = 0.f, a1 = 0.f, a2 = 0.f, a3 = 0.f;
    int e = 0;
    for (; e + 3 < cnt; e += 4) {
        int g0i = lst[e], g1i = lst[e + 1], g2i = lst[e + 2], g3i = lst[e + 3];
        float w0 = expf(pre_max[g0i] - m), w1 = expf(pre_max[g1i] - m);
        float w2 = expf(pre_max[g2i] - m), w3 = expf(pre_max[g3i] - m);
        a0 += w0 * x[(long)qrow(g0i) * DD + t];
        a1 += w1 * x[(long)qrow(g1i) * DD + t];
        a2 += w2 * x[(long)qrow(g2i) * DD + t];
        a3 += w3 * x[(long)qrow(g3i) * DD + t];
    }
    for (; e < cnt; e++) {
        int gi = lst[e];
        a0 += expf(pre_max[gi] - m) * x[(long)qrow(gi) * DD + t];
    }
    pa_q[(long)b * DD + t] = ((a0 + a1) + (a2 + a3));
    if (t == 0) { pm_q[b] = m; ps_q[b] = S; }
}

// ---------- K3b: adapted prototypes, phase B — combine + normalize ----------
__global__ __launch_bounds__(256) void adapt_comb_kernel(const float* __restrict__ proto,
                                                         const float* __restrict__ selfs,
                                                         const float* __restrict__ pm_q,
                                                         const float* __restrict__ ps_q,
                                                         const float* __restrict__ pa_q,
                                                         float* __restrict__ apn) {
    __shared__ float red[256];
    int c = blockIdx.x, t = threadIdx.x;
    float m0 = pm_q[c * 4 + 0], m1 = pm_q[c * 4 + 1];
    float m2 = pm_q[c * 4 + 2], m3 = pm_q[c * 4 + 3];
    float m = fmaxf(fmaxf(fmaxf(m0, m1), fmaxf(m2, m3)), selfs[c]);
    float w0 = expf(m0 - m), w1 = expf(m1 - m);   // expf(-inf)=0 for empty quarters
    float w2 = expf(m2 - m), w3 = expf(m3 - m);
    float es = expf(selfs[c] - m);
    float Z = ps_q[c * 4 + 0] * w0 + ps_q[c * 4 + 1] * w1
            + ps_q[c * 4 + 2] * w2 + ps_q[c * 4 + 3] * w3 + es;
    float A = pa_q[(long)(c * 4 + 0) * DD + t] * w0
            + pa_q[(long)(c * 4 + 1) * DD + t] * w1
            + pa_q[(long)(c * 4 + 2) * DD + t] * w2
            + pa_q[(long)(c * 4 + 3) * DD + t] * w3
            + es * proto[c * DD + t];
    float ap = A / Z;
    float n2 = blk_reduce_sum(ap * ap, red);
    apn[c * DD + t] = ap / sqrtf(n2);
}

// ---------- K4: bf16 MFMA coarse cosines — BATCH-BITONIC top-12 scan ----------
// (R12 verified. Unchanged.)
#define CASD(A, B) { unsigned int _x = (A), _y = (B); (A) = _x > _y ? _x : _y; (B) = _x > _y ? _y : _x; }
#define CASA(A, B) { unsigned int _x = (A), _y = (B); (A) = _x < _y ? _x : _y; (B) = _x < _y ? _y : _x; }

#define COMPUTE_TILE_L(LBUF, TILE)                                                 \
    {                                                                              \
        f32x4 accE = {2.f, 2.f, 2.f, 2.f};                                         \
        f32x4 accO = {0.f, 0.f, 0.f, 0.f};                                         \
        _Pragma("unroll")                                                          \
        for (int kc = 0; kc < 8; kc += 2) {                                        \
            short8 cfe = *(const short8*)((LBUF) + ((nn << 8) + ((((kc + 0) * 4 + qd) ^ xm) << 3))); \
            short8 cfo = *(const short8*)((LBUF) + ((nn << 8) + ((((kc + 1) * 4 + qd) ^ xm) << 3))); \
            accE = __builtin_amdgcn_mfma_f32_16x16x32_bf16(cfe, qh[kc + 0], accE, 0, 0, 0); \
            accO = __builtin_amdgcn_mfma_f32_16x16x32_bf16(cfo, qh[kc + 1], accO, 0, 0, 0); \
        }                                                                          \
        const unsigned int cb_ = (unsigned int)((TILE) * 16 + 4 * qd);             \
        unsigned int v0 = (__float_as_uint(accE[0] + accO[0]) & 0xFFFFFC00u) | (cb_ + 0); \
        unsigned int v1 = (__float_as_uint(accE[1] + accO[1]) & 0xFFFFFC00u) | (cb_ + 1); \
        unsigned int v2 = (__float_as_uint(accE[2] + accO[2]) & 0xFFFFFC00u) | (cb_ + 2); \
        unsigned int v3 = (__float_as_uint(accE[3] + accO[3]) & 0xFFFFFC00u) | (cb_ + 3); \
        /* sort batch ascending: v0<=v1<=v2<=v3 */                                 \
        CASA(v0, v1) CASA(v2, v3) CASA(v0, v2) CASA(v1, v3) CASA(v1, v2)           \
        /* split16 (valley keys[0..11]++v[0..3]); (i,i+8) for i<4 are no-ops */    \
        unsigned int t4 = keys[4], t5 = keys[5], t6 = keys[6], t7 = keys[7];       \
        unsigned int b4 = t4 < v0 ? t4 : v0; t4 = t4 > v0 ? t4 : v0;               \
        unsigned int b5 = t5 < v1 ? t5 : v1; t5 = t5 > v1 ? t5 : v1;               \
        unsigned int b6 = t6 < v2 ? t6 : v2; t6 = t6 > v2 ? t6 : v2;               \
        unsigned int b7 = t7 < v3 ? t7 : v3; t7 = t7 > v3 ? t7 : v3;               \
        /* sort top-8 [keys0..3, t4..7] desc (bitonic) */                          \
        CASD(keys[0], t4) CASD(keys[1], t5) CASD(keys[2], t6) CASD(keys[3], t7)    \
        CASD(keys[0], keys[2]) CASD(keys[1], keys[3]) CASD(t4, t6) CASD(t5, t7)    \
        CASD(keys[0], keys[1]) CASD(keys[2], keys[3]) CASD(t4, t5) CASD(t6, t7)    \
        keys[4] = t4; keys[5] = t5; keys[6] = t6; keys[7] = t7;                    \
        /* bottom-8 [keys8..11, b4..7] bitonic: top-4 via split (max only) */      \
        unsigned int B0 = keys[8]  > b4 ? keys[8]  : b4;                           \
        unsigned int B1 = keys[9]  > b5 ? keys[9]  : b5;                           \
        unsigned int B2 = keys[10] > b6 ? keys[10] : b6;                           \
        unsigned int B3 = keys[11] > b7 ? keys[11] : b7;                           \
        CASD(B0, B2) CASD(B1, B3) CASD(B0, B1) CASD(B2, B3)                        \
        keys[8] = B0; keys[9] = B1; keys[10] = B2; keys[11] = B3;                  \
    }

#define GLOAD(RA, RB, TL)                                                          \
    {                                                                              \
        const unsigned short* tb = xh + ((size_t)(col0 + (TL) * 16) << 8);         \
        RA = *(const uint4*)(tb + (G0 << 3));                                      \
        RB = *(const uint4*)(tb + (G1 << 3));                                      \
    }

#define DSWRITE(P, RA, RB)                                                         \
    {                                                                              \
        *(uint4*)((P) + (u0 << 3)) = RA;                                           \
        *(uint4*)((P) + (u1 << 3)) = RB;                                           \
    }

__global__ __launch_bounds__(256, 4) void simtopk_kernel(const unsigned short* __restrict__ xh,
                                                         int* __restrict__ topi4) {
    __shared__ uint4 smem4[2048];   // 32 KB: 2 buffers x 2 tiles; dump alias 13.3KB
    unsigned short* Tb = (unsigned short*)smem4;

    const int t = threadIdx.x;
    const int b = blockIdx.x;
    const int rb = b >> 3;          // 128 row-blocks of 64 rows
    const int ch = b & 7;           // column chunk (== XCD id under round-robin: L2-local)
    const int row0 = rb * 64;
    const int col0 = ch * 1024;

    const int wv = t >> 6;
    const int lane = t & 63;
    const int qd = lane >> 4;
    const int nn = lane & 15;
    const int xm = nn & 7;

    // staging geometry: tile = 512 x 16B units; thread handles G0=t, G1=256+t
    const int G0 = t, G1 = 256 + t;
    const int r0r = G0 >> 5, c0u = G0 & 31;
    const int u0 = r0r * 32 + (c0u ^ (r0r & 7));
    const int r1r = G1 >> 5, c1u = G1 & 31;
    const int u1 = r1r * 32 + (c1u ^ (r1r & 7));

    // Query fragments (MFMA B operand): lane holds Q[n=nn][k=kc*32+qd*8 ..+7]
    const int arow = (row0 + wv * 16 + nn) * DD;
    short8 qh[8];
    #pragma unroll
    for (int kc = 0; kc < 8; kc++)
        qh[kc] = *(const short8*)(xh + arow + kc * 32 + qd * 8);

    unsigned int keys[QK];
    #pragma unroll
    for (int s = 0; s < QK; s++) keys[s] = 0u;

    uint4 RA, RB, RC, RD;
    GLOAD(RA, RB, 0)
    GLOAD(RC, RD, 1)
    DSWRITE(Tb, RA, RB)
    DSWRITE(Tb + 4096, RC, RD)
    __syncthreads();                         // tiles 0,1 ready in buffer 0

    #pragma unroll 1
    for (int p = 0; p < 32; ++p) {
        const int cur = (p & 1) << 13;       // 0 / 8192 shorts (16KB buffers)
        if (p < 31) { GLOAD(RA, RB, 2 * p + 2) GLOAD(RC, RD, 2 * p + 3) }
        COMPUTE_TILE_L(Tb + cur, 2 * p)
        COMPUTE_TILE_L(Tb + cur + 4096, 2 * p + 1)
        if (p < 31) {
            DSWRITE(Tb + (cur ^ 8192), RA, RB)
            DSWRITE(Tb + (cur ^ 8192) + 4096, RC, RD)
        }
        __syncthreads();                     // publishes pair p+1; orders reads of pair p
    }

    // dump (wave-private region, in-order DS: no barrier) + 4-list merge.
    unsigned int* dw = (unsigned int*)smem4 + wv * 832;
    #pragma unroll
    for (int s = 0; s < QK; s++) dw[lane * 13 + s] = keys[s];
    if (lane < 16) {
        const int g = row0 + wv * 16 + lane;
        const int b0 = (lane +  0) * 13;
        const int b1 = (lane + 16) * 13;
        const int b2 = (lane + 32) * 13;
        const int b3 = (lane + 48) * 13;
        int p0 = 0, p1 = 0, p2 = 0, p3 = 0;
        for (int s = 0; s < QK; s++) {
            unsigned int v0 = (p0 < QK) ? dw[b0 + p0] : 0u;
            unsigned int v1 = (p1 < QK) ? dw[b1 + p1] : 0u;
            unsigned int v2 = (p2 < QK) ? dw[b2 + p2] : 0u;
            unsigned int v3 = (p3 < QK) ? dw[b3 + p3] : 0u;
            unsigned int bv = v0; int bw = 0;
            if (v1 > bv) { bv = v1; bw = 1; }
            if (v2 > bv) { bv = v2; bw = 2; }
            if (v3 > bv) { bv = v3; bw = 3; }
            topi4[g * CAND + ch * QK + s] = col0 + (int)(bv & 1023u);
            if (bw == 0) p0++; else if (bw == 1) p1++; else if (bw == 2) p2++; else p3++;
        }
    }
}

// ---------- K5: rescoring — 16-lane groups, coalesced, 1 DS-op/candidate ----------
// (R16 verified: off the top-5. Unchanged.)
__global__ __launch_bounds__(256, 4) void rescore_kernel(const float* __restrict__ x,
                                                         const float* __restrict__ qInv,
                                                         const int* __restrict__ topi4,
                                                         float* __restrict__ topv,
                                                         int* __restrict__ topi) {
    __shared__ float sc[CAND];
    __shared__ int   si[CAND];
    const int g = blockIdx.x;
    const int t = threadIdx.x;
    const int lane = t & 63;
    const int w = t >> 6;            // wave's candidate group [24w, 24w+24)
    const int gr = lane >> 4;        // 16-lane group 0..3
    const int sub = lane & 15;
    const float qg = qInv[g];
    const float4* a4 = (const float4*)(x + (long)qrow(g) * DD);
    float4 aq[4];
    #pragma unroll
    for (int k = 0; k < 4; k++) aq[k] = a4[k * 16 + sub];   // query elems [k*64+sub*4..+3]
    const int cb = g * CAND + w * 24;
    #pragma unroll 1
    for (int pass = 0; pass < 3; ++pass) {
        const int c0 = pass * 8 + gr;
        const int c1 = pass * 8 + 4 + gr;
        int j0 = topi4[cb + c0]; j0 = ((unsigned)j0 < NQ) ? j0 : 0;
        int j1 = topi4[cb + c1]; j1 = ((unsigned)j1 < NQ) ? j1 : 0;
        const float4* b40 = (const float4*)(x + (long)qrow(j0) * DD);
        const float4* b41 = (const float4*)(x + (long)qrow(j1) * DD);
        float p0 = 0.f, p1 = 0.f;
        #pragma unroll
        for (int k = 0; k < 4; k++) {
            float4 b0 = b40[k * 16 + sub];
            float4 b1 = b41[k * 16 + sub];
            p0 = fmaf(aq[k].x, b0.x, p0); p0 = fmaf(aq[k].y, b0.y, p0);
            p0 = fmaf(aq[k].z, b0.z, p0); p0 = fmaf(aq[k].w, b0.w, p0);
            p1 = fmaf(aq[k].x, b1.x, p1); p1 = fmaf(aq[k].y, b1.y, p1);
            p1 = fmaf(aq[k].z, b1.z, p1); p1 = fmaf(aq[k].w, b1.w, p1);
        }
        #pragma unroll
        for (int off = 8; off > 0; off >>= 1) {
            p0 += __shfl_xor(p0, off);
            p1 += __shfl_xor(p1, off);
        }
        if (sub == 0) {
            sc[w * 24 + c0] = p0 * qInv[j0] * qg; si[w * 24 + c0] = j0;
            sc[w * 24 + c1] = p1 * qInv[j1] * qg; si[w * 24 + c1] = j1;
        }
    }
    __syncthreads();
    if (t < 64) {
        float v0 = sc[lane];
        int   i0 = si[lane];
        float v1 = -INFINITY; int i1 = 0x7fffffff;
        if (lane < CAND - 64) { v1 = sc[64 + lane]; i1 = si[64 + lane]; }
        #pragma unroll 1
        for (int s = 0; s < KNB; ++s) {
            bool sel1 = (v1 > v0) || (v1 == v0 && i1 < i0);
            float bv = sel1 ? v1 : v0;
            int   bi = sel1 ? i1 : i0;
            #pragma unroll
            for (int off = 32; off > 0; off >>= 1) {
                float ov = __shfl_xor(bv, off);
                int   oi = __shfl_xor(bi, off);
                bool take = (ov > bv) || (ov == bv && oi < bi);
                bv = take ? ov : bv;
                bi = take ? oi : bi;
            }
            if (lane == 0) { topv[g * KNB + s] = bv; topi[g * KNB + s] = bi; }
            if (i0 == bi) v0 = -INFINITY;
            if (i1 == bi) v1 = -INFINITY;
        }
    }
}

// ---------- K6: mutual-kNN softmax, adapted query, final cos sims ----------
// (R17 verified: off the top-5. Unchanged.)
__global__ __launch_bounds__(256, 8) void final_kernel(const float* __restrict__ x,
                                                       const float* __restrict__ apn,
                                                       const float* __restrict__ topv,
                                                       const int* __restrict__ topi,
                                                       const float* __restrict__ tao_raw,
                                                       float* out) {
    __shared__ float tv[KNB]; __shared__ int ti[KNB]; __shared__ float w[KNB];
    __shared__ int mutf[KNB * KNB];
    __shared__ __align__(16) float aq2[272];
    __shared__ float red4[4];
    __shared__ float part[256];
    int i = blockIdx.x, t = threadIdx.x;
    const int lane = t & 63, wv = t >> 6;
    if (t < KNB) {
        tv[t] = topv[i * KNB + t];
        int j = topi[i * KNB + t];
        ti[t] = ((unsigned)j < NQ) ? j : 0;
    }
    __syncthreads();
    if (t < KNB * KNB) {                        // parallel mutual: 100 loads in flight
        const int s = t / KNB, u = t - s * KNB;
        mutf[t] = (topi[ti[s] * KNB + u] == i) ? 1 : 0;
    }
    __syncthreads();
    if (t < 16) {                               // OR-reduce flags + wave softmax
        float val = -INFINITY;
        if (t < KNB) {
            const int* mf = &mutf[t * KNB];
            int any = mf[0] | mf[1] | mf[2] | mf[3] | mf[4]
                    | mf[5] | mf[6] | mf[7] | mf[8] | mf[9];
            val = any ? tv[t] : -INFINITY;
        }
        float m = val;
        #pragma unroll
        for (int off = 8; off > 0; off >>= 1) m = fmaxf(m, __shfl_xor(m, off));
        float e = (t < KNB) ? expf(val - m) : 0.f;
        float Z = e;
        #pragma unroll
        for (int off = 8; off > 0; off >>= 1) Z += __shfl_xor(Z, off);
        if (t < KNB) w[t] = e / Z;
    }
    __syncthreads();
    // preload weights + indices to registers, then batch all 10 row gathers
    float wr[KNB]; int tr[KNB];
    #pragma unroll
    for (int s = 0; s < KNB; s++) { wr[s] = w[s]; tr[s] = ti[s]; }
    float xv[KNB];
    #pragma unroll
    for (int s = 0; s < KNB; s++) xv[s] = x[(long)qrow(tr[s]) * DD + t];
    float a = 0.f;
    #pragma unroll
    for (int s = 0; s < KNB; s++) a += wr[s] * xv[s];
    aq2[t + (t >> 6) * 4] = a;
    float v2 = a * a;
    #pragma unroll
    for (int off = 32; off > 0; off >>= 1) v2 += __shfl_xor(v2, off);
    if (lane == 0) red4[wv] = v2;
    __syncthreads();                            // publishes aq2 + red4
    float n2 = red4[0] + red4[1] + red4[2] + red4[3];
    float inv = 1.f / sqrtf(n2);
    int c = t >> 2, tl = t & 3;
    float sdot = 0.f;
    #pragma unroll
    for (int u4 = 0; u4 < 16; u4++) {
        float4 av = *(const float4*)(aq2 + u4 * 16 + (u4 >> 2) * 4 + tl * 4);
        float4 pv = *(const float4*)(apn + c * DD + u4 * 16 + tl * 4);
        sdot += av.x * pv.x; sdot += av.y * pv.y; sdot += av.z * pv.z; sdot += av.w * pv.w;
    }
    part[t] = sdot; __syncthreads();
    if (tl == 0) {
        float sv = part[t] + part[t + 1] + part[t + 2] + part[t + 3];
        out[i * NCLS + c] = tao_raw[0] * sv * inv;
    }
}

extern "C" void kernel_launch(void* const* d_in, const int* in_sizes, int n_in,
                              void* d_out, int out_size, void* d_ws, size_t ws_size,
                              hipStream_t stream) {
    (void)in_sizes; (void)n_in; (void)out_size;
    const float* x   = (const float*)d_in[0];
    const float* tao = (const float*)d_in[1];
    float* out = (float*)d_out;

    char* ws = (char*)d_ws;
    size_t off = 0;
    auto carve = [&](size_t bytes) {
        void* p = ws + off;
        off = (off + bytes + 255) & ~(size_t)255;
        return p;
    };
    float*          proto   = (float*)carve(NCLS * DD * 4);
    float*          pn      = (float*)carve(NCLS * DD * 4);
    float*          selfs   = (float*)carve(NCLS * 4);
    float*          qInv    = (float*)carve(NQ * 4);
    float*          pre_max = (float*)carve(NQ * 4);
    int*            pre_lab = (int*)carve(NQ * 4);
    float*          apn     = (float*)carve(NCLS * DD * 4);
    unsigned short* xh      = (unsigned short*)carve((size_t)NQ * DD * 2);
    int*            topi4   = (int*)carve((size_t)NQ * CAND * 4);
    float*          topv    = (float*)carve((size_t)NQ * KNB * 4);
    int*            topi    = (int*)carve((size_t)NQ * KNB * 4);
    float*          pm_q    = (float*)carve(NCLS * 4 * 4);
    float*          ps_q    = (float*)carve(NCLS * 4 * 4);
    float*          pa_q    = (float*)carve((size_t)NCLS * 4 * DD * 4);
    if (off > ws_size) return;

    proto_kernel<<<NCLS, 256, 0, stream>>>(x, proto, pn, selfs);
    presim_kernel<<<NQ, 256, 0, stream>>>(x, pn, xh, qInv, pre_max, pre_lab);
    adapt_part_kernel<<<NCLS * 4, 256, 0, stream>>>(x, pre_max, pre_lab, pm_q, ps_q, pa_q);
    adapt_comb_kernel<<<NCLS, 256, 0, stream>>>(proto, selfs, pm_q, ps_q, pa_q, apn);
    simtopk_kernel<<<NQ / 64 * NCH, 256, 0, stream>>>(xh, topi4);
    rescore_kernel<<<NQ, 256, 0, stream>>>(x, qInv, topi4, topv, topi);
    final_kernel<<<NQ, 256, 0, stream>>>(x, apn, topv, topi, tao, out);
}